// Round 2
// baseline (3714.330 us; speedup 1.0000x reference)
//
#include <hip/hip_runtime.h>
#include <hip/hip_bf16.h>

#define DEV __device__ __forceinline__

typedef __attribute__((ext_vector_type(4))) float f32x4;
typedef __attribute__((ext_vector_type(8))) short s16x8;
typedef unsigned short u16;

constexpr int Bsz = 8;      // batch
constexpr int S   = 2048;   // sequence
constexpr int Dm  = 512;    // model dim
constexpr int NHd = 8;      // heads
constexpr int FFd = 2048;
constexpr int Ln  = 4;
constexpr int T   = S * Bsz; // 16384 tokens

DEV u16 f2bf(float f) {
  union { float f; unsigned u; } v; v.f = f;
  unsigned r = v.u + 0x7fff + ((v.u >> 16) & 1);
  return (u16)(r >> 16);
}
DEV float bf2f(u16 a) { union { unsigned u; float f; } v; v.u = ((unsigned)a) << 16; return v.f; }

typedef __attribute__((address_space(1))) const unsigned int guint;
typedef __attribute__((address_space(3))) unsigned int luint;
DEV void gload16(const void* g, void* l) {
  __builtin_amdgcn_global_load_lds((guint*)g, (luint*)l, 16, 0, 0);
}

// ---------------- weight fp32 -> bf16 ----------------
__global__ void cvt_bf16_kernel(const float* __restrict__ src, u16* __restrict__ dst, int n4) {
  int i = (blockIdx.x * 256 + threadIdx.x);
  if (i >= n4) return;
  float4 v = *reinterpret_cast<const float4*>(src + i * 4);
  ushort4 o; o.x = f2bf(v.x); o.y = f2bf(v.y); o.z = f2bf(v.z); o.w = f2bf(v.w);
  *reinterpret_cast<ushort4*>(dst + i * 4) = o;
}

// ---------------- embed + positional encoding ----------------
__global__ void embed_kernel(const float* __restrict__ x, const float* __restrict__ Wemb,
                             const float* __restrict__ bemb, float* __restrict__ hf,
                             u16* __restrict__ hb) {
  int t = blockIdx.x;            // token = s*B + b
  int s = t >> 3, b = t & 7;
  const float* xr = x + ((size_t)b * S + s) * 14;
  float xv[14];
  #pragma unroll
  for (int i = 0; i < 14; i++) xv[i] = xr[i];
  for (int d = threadIdx.x; d < Dm; d += blockDim.x) {
    const float* wr = Wemb + d * 14;
    float acc = bemb[d];
    #pragma unroll
    for (int i = 0; i < 14; i++) acc += xv[i] * wr[i];
    float ang = (float)s * expf((float)((d >> 1) * 2) * (-9.210340371976184f / 512.0f));
    acc += (d & 1) ? cosf(ang) : sinf(ang);
    hf[(size_t)t * Dm + d] = acc;
    hb[(size_t)t * Dm + d] = f2bf(acc);
  }
}

// ---------------- GEMM: C(M,N) = A(M,K) @ Bt(N,K)^T + bias ----------------
// OMODE: 0 = f32 out, 1 = bf16 out, 2 = bf16 out + relu
template<int OMODE>
__global__ __launch_bounds__(256, 2)
void gemm_bt_kernel(const u16* __restrict__ A, const u16* __restrict__ Bt,
                    const float* __restrict__ bias, void* __restrict__ Cout,
                    int M, int N, int K) {
  __shared__ __align__(16) u16 As[128 * 32];
  __shared__ __align__(16) u16 Bs[128 * 32];
  const int tid = threadIdx.x;
  const int lane = tid & 63, w = tid >> 6;
  const int wr = w >> 1, wc = w & 1;
  const int lr = lane & 15, lg = lane >> 4;
  const int m0 = blockIdx.y * 128, n0 = blockIdx.x * 128;

  f32x4 acc[4][4] = {};

  const int c1 = tid, c2 = tid + 256;
  const u16* gA1 = A + (size_t)(m0 + (c1 >> 2)) * K + (c1 & 3) * 8;
  const u16* gA2 = A + (size_t)(m0 + (c2 >> 2)) * K + (c2 & 3) * 8;
  const u16* gB1 = Bt + (size_t)(n0 + (c1 >> 2)) * K + (c1 & 3) * 8;
  const u16* gB2 = Bt + (size_t)(n0 + (c2 >> 2)) * K + (c2 & 3) * 8;
  u16* lA1 = As + c1 * 8; u16* lA2 = As + c2 * 8;
  u16* lB1 = Bs + c1 * 8; u16* lB2 = Bs + c2 * 8;

  for (int kt = 0; kt < K; kt += 32) {
    __syncthreads();
    gload16(gA1 + kt, lA1); gload16(gA2 + kt, lA2);
    gload16(gB1 + kt, lB1); gload16(gB2 + kt, lB2);
    __syncthreads();
    s16x8 a[4], bb[4];
    #pragma unroll
    for (int i = 0; i < 4; i++) {
      a[i]  = *reinterpret_cast<const s16x8*>(As + ((wr * 64 + i * 16 + lr) * 32 + lg * 8));
      bb[i] = *reinterpret_cast<const s16x8*>(Bs + ((wc * 64 + i * 16 + lr) * 32 + lg * 8));
    }
    #pragma unroll
    for (int mi = 0; mi < 4; mi++)
      #pragma unroll
      for (int ni = 0; ni < 4; ni++)
        acc[mi][ni] = __builtin_amdgcn_mfma_f32_16x16x32_bf16(a[mi], bb[ni], acc[mi][ni], 0, 0, 0);
  }

  #pragma unroll
  for (int mi = 0; mi < 4; mi++) {
    int row = m0 + wr * 64 + mi * 16 + lg * 4;
    #pragma unroll
    for (int ni = 0; ni < 4; ni++) {
      int col = n0 + wc * 64 + ni * 16 + lr;
      float bv = bias[col];
      #pragma unroll
      for (int r = 0; r < 4; r++) {
        float v = acc[mi][ni][r] + bv;
        if (OMODE == 2) v = v > 0.f ? v : 0.f;
        if (OMODE == 0) ((float*)Cout)[(size_t)(row + r) * N + col] = v;
        else            ((u16*)Cout)[(size_t)(row + r) * N + col] = f2bf(v);
      }
    }
  }
}

// ---------------- pack qkv -> per-(b,h) contiguous Q,K + transposed V ----------------
// q_pk[bh][s][64] (scaled by 0.125), k_pk[bh][s][64], v_pk[bh][64][S]
__global__ void pack_qkv_kernel(const u16* __restrict__ qkv, u16* __restrict__ q_pk,
                                u16* __restrict__ k_pk, u16* __restrict__ v_pk) {
  __shared__ u16 tile[64][66];
  int st = blockIdx.x, b = blockIdx.y, h = blockIdx.z;
  int tid = threadIdx.x;

  // V: stage 64x64 tile in LDS (rows = s), then write transposed
  #pragma unroll
  for (int p = 0; p < 4; p++) {
    int s = p * 16 + (tid >> 4);
    int dq = (tid & 15) * 4;
    size_t tok = (size_t)(st * 64 + s) * Bsz + b;
    ushort4 val = *reinterpret_cast<const ushort4*>(qkv + tok * 1536 + 1024 + h * 64 + dq);
    tile[s][dq] = val.x; tile[s][dq + 1] = val.y; tile[s][dq + 2] = val.z; tile[s][dq + 3] = val.w;
  }

  // Q (scaled) and K copies, coalesced 32B per thread
  {
    int s = tid >> 2, part = tid & 3;
    size_t tok = (size_t)(st * 64 + s) * Bsz + b;
    const u16* src = qkv + tok * 1536 + h * 64 + part * 16;
    size_t drow = ((size_t)(b * NHd + h) * S + st * 64 + s) * 64 + part * 16;
    s16x8 v0 = *reinterpret_cast<const s16x8*>(src);
    s16x8 v1 = *reinterpret_cast<const s16x8*>(src + 8);
    s16x8 o0, o1;
    #pragma unroll
    for (int j = 0; j < 8; j++) {
      o0[j] = (short)f2bf(bf2f((u16)v0[j]) * 0.125f);
      o1[j] = (short)f2bf(bf2f((u16)v1[j]) * 0.125f);
    }
    *reinterpret_cast<s16x8*>(q_pk + drow) = o0;
    *reinterpret_cast<s16x8*>(q_pk + drow + 8) = o1;
    s16x8 k0 = *reinterpret_cast<const s16x8*>(src + 512);
    s16x8 k1 = *reinterpret_cast<const s16x8*>(src + 512 + 8);
    *reinterpret_cast<s16x8*>(k_pk + drow) = k0;
    *reinterpret_cast<s16x8*>(k_pk + drow + 8) = k1;
  }

  __syncthreads();
  #pragma unroll
  for (int p = 0; p < 4; p++) {
    int d = p * 16 + (tid >> 4);
    int s4 = (tid & 15) * 4;
    ushort4 o;
    o.x = tile[s4][d]; o.y = tile[s4 + 1][d]; o.z = tile[s4 + 2][d]; o.w = tile[s4 + 3][d];
    *reinterpret_cast<ushort4*>(v_pk + ((size_t)(b * NHd + h) * 64 + d) * S + st * 64 + s4) = o;
  }
}

// ---------------- flash attention v2 (packed inputs, windowed via s_base) ----------------
__global__ __launch_bounds__(256, 4)
void flash_kernel(const u16* __restrict__ q_pk, const u16* __restrict__ k_pk,
                  const u16* __restrict__ v_pk, u16* __restrict__ ctx, int S_att) {
  const int tid = threadIdx.x;
  const int lane = tid & 63, w = tid >> 6;
  const int lr = lane & 15, lg = lane >> 4;
  const int combo = blockIdx.y, h = blockIdx.z;
  const int b = combo & 7, n = combo >> 3;
  const int s_base = n * S_att;
  const int q0 = blockIdx.x * 64 + w * 16;
  const int bh = b * NHd + h;

  __shared__ __align__(16) u16 p_lds_all[4][16][72];
  u16 (*p_lds)[72] = p_lds_all[w];

  const u16* qbase = q_pk + ((size_t)bh * S + s_base + q0) * 64;
  const u16* kbase = k_pk + ((size_t)bh * S + s_base) * 64;
  const u16* vbase = v_pk + (size_t)bh * 64 * S + s_base;

  s16x8 qf[2];
  qf[0] = *reinterpret_cast<const s16x8*>(qbase + (size_t)lr * 64 + lg * 8);
  qf[1] = *reinterpret_cast<const s16x8*>(qbase + (size_t)lr * 64 + lg * 8 + 32);

  s16x8 ones;
  #pragma unroll
  for (int j = 0; j < 8; j++) ones[j] = (short)0x3F80;  // bf16 1.0

  float mrow[4]; f32x4 lacc = (f32x4){0.f, 0.f, 0.f, 0.f}; f32x4 oacc[4];
  #pragma unroll
  for (int r = 0; r < 4; r++) mrow[r] = -1e30f;
  #pragma unroll
  for (int nt = 0; nt < 4; nt++) oacc[nt] = (f32x4){0.f, 0.f, 0.f, 0.f};

  for (int kb = 0; kb < S_att; kb += 64) {
    // QK^T (Q pre-scaled by 1/8)
    f32x4 sg[4];
    __builtin_amdgcn_s_setprio(1);
    #pragma unroll
    for (int g = 0; g < 4; g++) {
      const u16* kp = kbase + (size_t)(kb + g * 16 + lr) * 64 + lg * 8;
      s16x8 k0 = *reinterpret_cast<const s16x8*>(kp);
      s16x8 k1 = *reinterpret_cast<const s16x8*>(kp + 32);
      f32x4 sc = (f32x4){0.f, 0.f, 0.f, 0.f};
      sc = __builtin_amdgcn_mfma_f32_16x16x32_bf16(qf[0], k0, sc, 0, 0, 0);
      sc = __builtin_amdgcn_mfma_f32_16x16x32_bf16(qf[1], k1, sc, 0, 0, 0);
      sg[g] = sc;
    }
    __builtin_amdgcn_s_setprio(0);

    // V fragments preloaded BEFORE the LDS fences: latency hides under softmax
    s16x8 vf[2][4];
    #pragma unroll
    for (int kc = 0; kc < 2; kc++)
      #pragma unroll
      for (int nt = 0; nt < 4; nt++)
        vf[kc][nt] = *reinterpret_cast<const s16x8*>(
            vbase + (size_t)(nt * 16 + lr) * S + kb + kc * 32 + lg * 8);

    // row max (reduce over lr lanes only; rows live in lg*4+r)
    float mnew[4]; bool chg = false;
    #pragma unroll
    for (int r = 0; r < 4; r++) {
      float mx = fmaxf(fmaxf(sg[0][r], sg[1][r]), fmaxf(sg[2][r], sg[3][r]));
      #pragma unroll
      for (int o = 8; o >= 1; o >>= 1) mx = fmaxf(mx, __shfl_xor(mx, o, 64));
      mnew[r] = fmaxf(mrow[r], mx);
      chg = chg || (mnew[r] > mrow[r]);
    }
    if (__any((int)chg)) {   // defer-max: skip rescale when no row max grew
      #pragma unroll
      for (int r = 0; r < 4; r++) {
        float corr = __expf(mrow[r] - mnew[r]);
        mrow[r] = mnew[r];
        lacc[r] *= corr;
        #pragma unroll
        for (int nt = 0; nt < 4; nt++) oacc[nt][r] *= corr;
      }
    }

    // P -> LDS (transpose to PV A-operand layout)
    asm volatile("s_waitcnt lgkmcnt(0)" ::: "memory");  // WAR vs previous iter's reads
    #pragma unroll
    for (int g = 0; g < 4; g++)
      #pragma unroll
      for (int r = 0; r < 4; r++)
        p_lds[lg * 4 + r][g * 16 + lr] = f2bf(__expf(sg[g][r] - mrow[r]));
    asm volatile("s_waitcnt lgkmcnt(0)" ::: "memory");  // RAW: writes visible within wave

    __builtin_amdgcn_s_setprio(1);
    #pragma unroll
    for (int kc = 0; kc < 2; kc++) {
      s16x8 pa = *reinterpret_cast<const s16x8*>(&p_lds[lr][kc * 32 + lg * 8]);
      lacc = __builtin_amdgcn_mfma_f32_16x16x32_bf16(pa, ones, lacc, 0, 0, 0);  // row-sum
      #pragma unroll
      for (int nt = 0; nt < 4; nt++)
        oacc[nt] = __builtin_amdgcn_mfma_f32_16x16x32_bf16(pa, vf[kc][nt], oacc[nt], 0, 0, 0);
    }
    __builtin_amdgcn_s_setprio(0);
  }

  #pragma unroll
  for (int nt = 0; nt < 4; nt++)
    #pragma unroll
    for (int r = 0; r < 4; r++) {
      float v = oacc[nt][r] / lacc[r];
      size_t tq = (size_t)(s_base + q0 + lg * 4 + r) * Bsz + b;
      ctx[tq * 512 + h * 64 + nt * 16 + lr] = f2bf(v);
    }
}

// ---------------- residual add (bf16 branches) + LayerNorm ----------------
template<int NADD>
__global__ void ln_kernel(const float* __restrict__ hin, const u16* __restrict__ a1,
                          const u16* __restrict__ a2, const float* __restrict__ gamma,
                          const float* __restrict__ beta, float* __restrict__ hf,
                          u16* __restrict__ hb) {
  int row = blockIdx.x * 4 + (threadIdx.x >> 6);
  int lane = threadIdx.x & 63;
  size_t base = (size_t)row * 512 + lane * 8;
  float4 h0 = *reinterpret_cast<const float4*>(hin + base);
  float4 h1 = *reinterpret_cast<const float4*>(hin + base + 4);
  s16x8 x1 = *reinterpret_cast<const s16x8*>(a1 + base);
  s16x8 x2 = {};
  if (NADD == 2) x2 = *reinterpret_cast<const s16x8*>(a2 + base);
  float v[8];
  float hv[8] = {h0.x, h0.y, h0.z, h0.w, h1.x, h1.y, h1.z, h1.w};
  float sum = 0.f;
  #pragma unroll
  for (int j = 0; j < 8; j++) {
    float t = hv[j] + bf2f((u16)x1[j]);
    if (NADD == 2) t += bf2f((u16)x2[j]);
    v[j] = t; sum += t;
  }
  #pragma unroll
  for (int o = 32; o >= 1; o >>= 1) sum += __shfl_xor(sum, o, 64);
  float mean = sum * (1.0f / 512.0f);
  float sq = 0.f;
  #pragma unroll
  for (int j = 0; j < 8; j++) { float d = v[j] - mean; sq += d * d; }
  #pragma unroll
  for (int o = 32; o >= 1; o >>= 1) sq += __shfl_xor(sq, o, 64);
  float rstd = rsqrtf(sq * (1.0f / 512.0f) + 1e-5f);
  #pragma unroll
  for (int j = 0; j < 8; j++) {
    int d = lane * 8 + j;
    float o = (v[j] - mean) * rstd * gamma[d] + beta[d];
    hf[base + j] = o;
    hb[base + j] = f2bf(o);
  }
}

// ---------------- final projection ----------------
__global__ void out_kernel(const float* __restrict__ hf, const float* __restrict__ Wout,
                           const float* __restrict__ bout, float* __restrict__ out) {
  int b = blockIdx.x; int lane = threadIdx.x;
  size_t base = ((size_t)(S - 1) * Bsz + b) * 512;
  float s = 0.f;
  #pragma unroll
  for (int j = 0; j < 8; j++) { int d = lane * 8 + j; s += hf[base + d] * Wout[d]; }
  #pragma unroll
  for (int o = 32; o >= 1; o >>= 1) s += __shfl_xor(s, o, 64);
  if (lane == 0) out[b] = s + bout[0];
}

extern "C" void kernel_launch(void* const* d_in, const int* in_sizes, int n_in,
                              void* d_out, int out_size, void* d_ws, size_t ws_size,
                              hipStream_t stream) {
  (void)in_sizes; (void)n_in; (void)out_size; (void)ws_size;
  const float* x      = (const float*)d_in[0];
  const float* W_emb  = (const float*)d_in[1];
  const float* b_emb  = (const float*)d_in[2];
  const float* Wqkv_g = (const float*)d_in[3];
  const float* bqkv_g = (const float*)d_in[4];
  const float* Wo_g   = (const float*)d_in[5];
  const float* bo_g   = (const float*)d_in[6];
  const float* Wqkv_l = (const float*)d_in[7];
  const float* bqkv_l = (const float*)d_in[8];
  const float* Wo_l   = (const float*)d_in[9];
  const float* bo_l   = (const float*)d_in[10];
  const float* W1     = (const float*)d_in[11];
  const float* b1f    = (const float*)d_in[12];
  const float* W2     = (const float*)d_in[13];
  const float* b2f    = (const float*)d_in[14];
  const float* g1     = (const float*)d_in[15];
  const float* be1    = (const float*)d_in[16];
  const float* g2     = (const float*)d_in[17];
  const float* be2    = (const float*)d_in[18];
  const float* W_out  = (const float*)d_in[19];
  const float* b_out  = (const float*)d_in[20];
  float* out = (float*)d_out;

  char* ws = (char*)d_ws;
  u16*   w_bf = (u16*)ws;                       // 32 MiB bf16 weights
  float* h_f  = (float*)(ws + 33554432);        // 32 MiB fp32 master
  u16*   h_b  = (u16*)(ws + 67108864);          // 16 MiB bf16 mirror
  u16*   qkv  = (u16*)(ws + 83886080);          // 48 MiB (dead after pack)
  u16*   q_pk = (u16*)(ws + 134217728);         // 16 MiB
  u16*   k_pk = (u16*)(ws + 150994944);         // 16 MiB
  u16*   v_pk = (u16*)(ws + 167772160);         // 16 MiB
  u16*   ctx  = (u16*)(ws + 83886080);          // 16 MiB, aliases dead qkv
  u16*   ff1  = (u16*)(ws + 83886080);          // 64 MiB, aliases dead qkv+q_pk
  u16*   go   = (u16*)(ws + 184549376);         // 16 MiB bf16 (also ff2)
  u16*   lo   = (u16*)(ws + 201326592);         // 16 MiB bf16 -> total 208 MiB

  u16* wqkvg = w_bf + 0;
  u16* wqkvl = w_bf + 3145728;
  u16* wog   = w_bf + 6291456;
  u16* wol   = w_bf + 7340032;
  u16* w1b   = w_bf + 8388608;
  u16* w2b   = w_bf + 12582912;

  auto cvt = [&](const float* s_, u16* d_, int n) {
    cvt_bf16_kernel<<<(n / 4 + 255) / 256, 256, 0, stream>>>(s_, d_, n / 4);
  };
  cvt(Wqkv_g, wqkvg, 3145728);
  cvt(Wqkv_l, wqkvl, 3145728);
  cvt(Wo_g,   wog,   1048576);
  cvt(Wo_l,   wol,   1048576);
  cvt(W1,     w1b,   4194304);
  cvt(W2,     w2b,   4194304);

  embed_kernel<<<T, 256, 0, stream>>>(x, W_emb, b_emb, h_f, h_b);

  for (int i = 0; i < Ln; i++) {
    // global attention
    gemm_bt_kernel<1><<<dim3(1536 / 128, T / 128), 256, 0, stream>>>(
        h_b, wqkvg + (size_t)i * 786432, bqkv_g + i * 1536, qkv, T, 1536, 512);
    pack_qkv_kernel<<<dim3(S / 64, Bsz, NHd), 256, 0, stream>>>(qkv, q_pk, k_pk, v_pk);
    flash_kernel<<<dim3(2048 / 64, 8, NHd), 256, 0, stream>>>(q_pk, k_pk, v_pk, ctx, 2048);
    gemm_bt_kernel<1><<<dim3(512 / 128, T / 128), 256, 0, stream>>>(
        ctx, wog + (size_t)i * 262144, bo_g + i * 512, go, T, 512, 512);
    // local (windowed) attention
    gemm_bt_kernel<1><<<dim3(1536 / 128, T / 128), 256, 0, stream>>>(
        h_b, wqkvl + (size_t)i * 786432, bqkv_l + i * 1536, qkv, T, 1536, 512);
    pack_qkv_kernel<<<dim3(S / 64, Bsz, NHd), 256, 0, stream>>>(qkv, q_pk, k_pk, v_pk);
    flash_kernel<<<dim3(512 / 64, 32, NHd), 256, 0, stream>>>(q_pk, k_pk, v_pk, ctx, 512);
    gemm_bt_kernel<1><<<dim3(512 / 128, T / 128), 256, 0, stream>>>(
        ctx, wol + (size_t)i * 262144, bo_l + i * 512, lo, T, 512, 512);
    // LN1
    ln_kernel<2><<<T / 4, 256, 0, stream>>>(h_f, go, lo, g1 + i * 512, be1 + i * 512, h_f, h_b);
    // FFN
    gemm_bt_kernel<2><<<dim3(FFd / 128, T / 128), 256, 0, stream>>>(
        h_b, w1b + (size_t)i * 1048576, b1f + i * 2048, ff1, T, 2048, 512);
    gemm_bt_kernel<1><<<dim3(512 / 128, T / 128), 256, 0, stream>>>(
        ff1, w2b + (size_t)i * 1048576, b2f + i * 512, go, T, 512, 2048);
    ln_kernel<1><<<T / 4, 256, 0, stream>>>(h_f, go, nullptr, g2 + i * 512, be2 + i * 512, h_f, h_b);
  }

  out_kernel<<<Bsz, 64, 0, stream>>>(h_f, W_out, b_out, out);
}

// Round 3
// 2099.901 us; speedup vs baseline: 1.7688x; 1.7688x over previous
//
#include <hip/hip_runtime.h>
#include <hip/hip_bf16.h>

#define DEV __device__ __forceinline__

typedef __attribute__((ext_vector_type(4))) float f32x4;
typedef __attribute__((ext_vector_type(8))) short s16x8;
typedef unsigned short u16;

constexpr int Bsz = 8;      // batch
constexpr int S   = 2048;   // sequence
constexpr int Dm  = 512;    // model dim
constexpr int NHd = 8;      // heads
constexpr int FFd = 2048;
constexpr int Ln  = 4;
constexpr int T   = S * Bsz; // 16384 tokens

DEV u16 f2bf(float f) {
  union { float f; unsigned u; } v; v.f = f;
  unsigned r = v.u + 0x7fff + ((v.u >> 16) & 1);
  return (u16)(r >> 16);
}
DEV float bf2f(u16 a) { union { unsigned u; float f; } v; v.u = ((unsigned)a) << 16; return v.f; }

typedef __attribute__((address_space(1))) const unsigned int guint;
typedef __attribute__((address_space(3))) unsigned int luint;
DEV void gload16(const void* g, void* l) {
  __builtin_amdgcn_global_load_lds((guint*)g, (luint*)l, 16, 0, 0);
}

// ---------------- weight fp32 -> bf16 ----------------
__global__ void cvt_bf16_kernel(const float* __restrict__ src, u16* __restrict__ dst, int n4) {
  int i = (blockIdx.x * 256 + threadIdx.x);
  if (i >= n4) return;
  float4 v = *reinterpret_cast<const float4*>(src + i * 4);
  ushort4 o; o.x = f2bf(v.x); o.y = f2bf(v.y); o.z = f2bf(v.z); o.w = f2bf(v.w);
  *reinterpret_cast<ushort4*>(dst + i * 4) = o;
}

// ---------------- embed + positional encoding ----------------
__global__ void embed_kernel(const float* __restrict__ x, const float* __restrict__ Wemb,
                             const float* __restrict__ bemb, float* __restrict__ hf,
                             u16* __restrict__ hb) {
  int t = blockIdx.x;            // token = s*B + b
  int s = t >> 3, b = t & 7;
  const float* xr = x + ((size_t)b * S + s) * 14;
  float xv[14];
  #pragma unroll
  for (int i = 0; i < 14; i++) xv[i] = xr[i];
  for (int d = threadIdx.x; d < Dm; d += blockDim.x) {
    const float* wr = Wemb + d * 14;
    float acc = bemb[d];
    #pragma unroll
    for (int i = 0; i < 14; i++) acc += xv[i] * wr[i];
    float ang = (float)s * expf((float)((d >> 1) * 2) * (-9.210340371976184f / 512.0f));
    acc += (d & 1) ? cosf(ang) : sinf(ang);
    hf[(size_t)t * Dm + d] = acc;
    hb[(size_t)t * Dm + d] = f2bf(acc);
  }
}

// ---------------- GEMM: C(M,N) = A(M,K) @ Bt(N,K)^T + bias ----------------
// OMODE: 0 = f32 out, 1 = bf16 out, 2 = bf16 out + relu
template<int OMODE>
__global__ __launch_bounds__(256, 2)
void gemm_bt_kernel(const u16* __restrict__ A, const u16* __restrict__ Bt,
                    const float* __restrict__ bias, void* __restrict__ Cout,
                    int M, int N, int K) {
  __shared__ __align__(16) u16 As[128 * 32];
  __shared__ __align__(16) u16 Bs[128 * 32];
  const int tid = threadIdx.x;
  const int lane = tid & 63, w = tid >> 6;
  const int wr = w >> 1, wc = w & 1;
  const int lr = lane & 15, lg = lane >> 4;
  const int m0 = blockIdx.y * 128, n0 = blockIdx.x * 128;

  f32x4 acc[4][4] = {};

  const int c1 = tid, c2 = tid + 256;
  const u16* gA1 = A + (size_t)(m0 + (c1 >> 2)) * K + (c1 & 3) * 8;
  const u16* gA2 = A + (size_t)(m0 + (c2 >> 2)) * K + (c2 & 3) * 8;
  const u16* gB1 = Bt + (size_t)(n0 + (c1 >> 2)) * K + (c1 & 3) * 8;
  const u16* gB2 = Bt + (size_t)(n0 + (c2 >> 2)) * K + (c2 & 3) * 8;
  u16* lA1 = As + c1 * 8; u16* lA2 = As + c2 * 8;
  u16* lB1 = Bs + c1 * 8; u16* lB2 = Bs + c2 * 8;

  for (int kt = 0; kt < K; kt += 32) {
    __syncthreads();
    gload16(gA1 + kt, lA1); gload16(gA2 + kt, lA2);
    gload16(gB1 + kt, lB1); gload16(gB2 + kt, lB2);
    __syncthreads();
    s16x8 a[4], bb[4];
    #pragma unroll
    for (int i = 0; i < 4; i++) {
      a[i]  = *reinterpret_cast<const s16x8*>(As + ((wr * 64 + i * 16 + lr) * 32 + lg * 8));
      bb[i] = *reinterpret_cast<const s16x8*>(Bs + ((wc * 64 + i * 16 + lr) * 32 + lg * 8));
    }
    #pragma unroll
    for (int mi = 0; mi < 4; mi++)
      #pragma unroll
      for (int ni = 0; ni < 4; ni++)
        acc[mi][ni] = __builtin_amdgcn_mfma_f32_16x16x32_bf16(a[mi], bb[ni], acc[mi][ni], 0, 0, 0);
  }

  #pragma unroll
  for (int mi = 0; mi < 4; mi++) {
    int row = m0 + wr * 64 + mi * 16 + lg * 4;
    #pragma unroll
    for (int ni = 0; ni < 4; ni++) {
      int col = n0 + wc * 64 + ni * 16 + lr;
      float bv = bias[col];
      #pragma unroll
      for (int r = 0; r < 4; r++) {
        float v = acc[mi][ni][r] + bv;
        if (OMODE == 2) v = v > 0.f ? v : 0.f;
        if (OMODE == 0) ((float*)Cout)[(size_t)(row + r) * N + col] = v;
        else            ((u16*)Cout)[(size_t)(row + r) * N + col] = f2bf(v);
      }
    }
  }
}

// ---------------- pack qkv -> per-(b,h) contiguous Q,K + transposed V ----------------
// q_pk[bh][s][64] (scaled by 0.125), k_pk[bh][s][64], v_pk[bh][64][S]
__global__ void pack_qkv_kernel(const u16* __restrict__ qkv, u16* __restrict__ q_pk,
                                u16* __restrict__ k_pk, u16* __restrict__ v_pk) {
  __shared__ u16 tile[64][66];
  int st = blockIdx.x, b = blockIdx.y, h = blockIdx.z;
  int tid = threadIdx.x;

  // V: stage 64x64 tile in LDS (rows = s), then write transposed
  #pragma unroll
  for (int p = 0; p < 4; p++) {
    int s = p * 16 + (tid >> 4);
    int dq = (tid & 15) * 4;
    size_t tok = (size_t)(st * 64 + s) * Bsz + b;
    ushort4 val = *reinterpret_cast<const ushort4*>(qkv + tok * 1536 + 1024 + h * 64 + dq);
    tile[s][dq] = val.x; tile[s][dq + 1] = val.y; tile[s][dq + 2] = val.z; tile[s][dq + 3] = val.w;
  }

  // Q (scaled) and K copies, coalesced 32B per thread
  {
    int s = tid >> 2, part = tid & 3;
    size_t tok = (size_t)(st * 64 + s) * Bsz + b;
    const u16* src = qkv + tok * 1536 + h * 64 + part * 16;
    size_t drow = ((size_t)(b * NHd + h) * S + st * 64 + s) * 64 + part * 16;
    s16x8 v0 = *reinterpret_cast<const s16x8*>(src);
    s16x8 v1 = *reinterpret_cast<const s16x8*>(src + 8);
    s16x8 o0, o1;
    #pragma unroll
    for (int j = 0; j < 8; j++) {
      o0[j] = (short)f2bf(bf2f((u16)v0[j]) * 0.125f);
      o1[j] = (short)f2bf(bf2f((u16)v1[j]) * 0.125f);
    }
    *reinterpret_cast<s16x8*>(q_pk + drow) = o0;
    *reinterpret_cast<s16x8*>(q_pk + drow + 8) = o1;
    s16x8 k0 = *reinterpret_cast<const s16x8*>(src + 512);
    s16x8 k1 = *reinterpret_cast<const s16x8*>(src + 512 + 8);
    *reinterpret_cast<s16x8*>(k_pk + drow) = k0;
    *reinterpret_cast<s16x8*>(k_pk + drow + 8) = k1;
  }

  __syncthreads();
  #pragma unroll
  for (int p = 0; p < 4; p++) {
    int d = p * 16 + (tid >> 4);
    int s4 = (tid & 15) * 4;
    ushort4 o;
    o.x = tile[s4][d]; o.y = tile[s4 + 1][d]; o.z = tile[s4 + 2][d]; o.w = tile[s4 + 3][d];
    *reinterpret_cast<ushort4*>(v_pk + ((size_t)(b * NHd + h) * 64 + d) * S + st * 64 + s4) = o;
  }
}

// ---------------- flash attention v3: XCD-local grid + LDS-staged KV ----------------
// 1D grid, bid%8 = h (XCD pin), consecutive resident blocks share (b,h) -> L2 hits.
// K/V tiles staged to LDS via global_load_lds (dbuf, 2-phase), XOR-swizzled both sides.
__global__ __launch_bounds__(256, 3)
void flash_kernel(const u16* __restrict__ q_pk, const u16* __restrict__ k_pk,
                  const u16* __restrict__ v_pk, u16* __restrict__ ctx,
                  int S_att, int nqb) {
  const int tid = threadIdx.x;
  const int lane = tid & 63, w = tid >> 6;
  const int lr = lane & 15, lg = lane >> 4;
  const int bid = blockIdx.x;
  const int h = bid & 7;
  const int r_ = bid >> 3;
  const int qb = r_ % nqb;
  const int cw = r_ / nqb;
  const int b = cw & 7, n = cw >> 3;
  const int s_base = n * S_att;
  const int q0 = qb * 64 + w * 16;
  const int bh = b * NHd + h;

  __shared__ __align__(16) u16 KT[2][4096];   // [key 0..63][dk 0..63], seg-swizzled
  __shared__ __align__(16) u16 VT[2][4096];   // [d 0..63][k 0..63],    seg-swizzled
  __shared__ __align__(16) u16 p_lds_all[4][16][72];
  u16 (*p_lds)[72] = p_lds_all[w];

  const u16* qbase = q_pk + ((size_t)bh * S + s_base + q0) * 64;
  const u16* kbase = k_pk + ((size_t)bh * S + s_base) * 64;
  const u16* vbase = v_pk + (size_t)bh * 64 * S + s_base;

  s16x8 qf[2];
  qf[0] = *reinterpret_cast<const s16x8*>(qbase + (size_t)lr * 64 + lg * 8);
  qf[1] = *reinterpret_cast<const s16x8*>(qbase + (size_t)lr * 64 + lg * 8 + 32);

  s16x8 ones;
  #pragma unroll
  for (int j = 0; j < 8; j++) ones[j] = (short)0x3F80;  // bf16 1.0

  float mrow[4]; f32x4 lacc = (f32x4){0.f, 0.f, 0.f, 0.f}; f32x4 oacc[4];
  #pragma unroll
  for (int r = 0; r < 4; r++) mrow[r] = -1e30f;
  #pragma unroll
  for (int nt = 0; nt < 4; nt++) oacc[nt] = (f32x4){0.f, 0.f, 0.f, 0.f};

  // staging: thread t covers rows (t>>3) and (t>>3)+32, 16B segment (t&7),
  // global source pre-swizzled seg^=(row&7) so LDS dest stays linear (rule #21).
  const int seg = tid & 7, sr1 = tid >> 3, sr2 = (tid >> 3) + 32;
  const int ssw1 = (seg ^ (sr1 & 7)) * 8, ssw2 = (seg ^ (sr2 & 7)) * 8;

  auto stage = [&](int kb, int c) {
    const u16* kt = kbase + (size_t)kb * 64;
    gload16(kt + sr1 * 64 + ssw1, &KT[c][tid * 8]);
    gload16(kt + sr2 * 64 + ssw2, &KT[c][2048 + tid * 8]);
    const u16* vt = vbase + kb;
    gload16(vt + (size_t)sr1 * S + ssw1, &VT[c][tid * 8]);
    gload16(vt + (size_t)sr2 * S + ssw2, &VT[c][2048 + tid * 8]);
  };

  stage(0, 0);
  __syncthreads();

  for (int kb = 0; kb < S_att; kb += 64) {
    const int c = (kb >> 6) & 1;
    if (kb + 64 < S_att) stage(kb + 64, c ^ 1);   // prefetch: drains at end-of-iter barrier

    // QK^T from LDS (Q pre-scaled by 1/8)
    f32x4 sg[4];
    __builtin_amdgcn_s_setprio(1);
    #pragma unroll
    for (int g = 0; g < 4; g++) {
      const int key = g * 16 + lr, kw = key & 7;
      const u16* kp = &KT[c][key * 64];
      s16x8 k0 = *reinterpret_cast<const s16x8*>(kp + ((lg ^ kw) * 8));
      s16x8 k1 = *reinterpret_cast<const s16x8*>(kp + (((4 + lg) ^ kw) * 8));
      f32x4 sc = (f32x4){0.f, 0.f, 0.f, 0.f};
      sc = __builtin_amdgcn_mfma_f32_16x16x32_bf16(qf[0], k0, sc, 0, 0, 0);
      sc = __builtin_amdgcn_mfma_f32_16x16x32_bf16(qf[1], k1, sc, 0, 0, 0);
      sg[g] = sc;
    }
    __builtin_amdgcn_s_setprio(0);

    // row max (reduce over lr lanes; rows live in lg*4+r)
    float mnew[4]; bool chg = false;
    #pragma unroll
    for (int r = 0; r < 4; r++) {
      float mx = fmaxf(fmaxf(sg[0][r], sg[1][r]), fmaxf(sg[2][r], sg[3][r]));
      #pragma unroll
      for (int o = 8; o >= 1; o >>= 1) mx = fmaxf(mx, __shfl_xor(mx, o, 64));
      mnew[r] = fmaxf(mrow[r], mx);
      chg = chg || (mnew[r] > mrow[r]);
    }
    if (__any((int)chg)) {   // defer-max: skip rescale when no row max grew
      #pragma unroll
      for (int r = 0; r < 4; r++) {
        float corr = __expf(mrow[r] - mnew[r]);
        mrow[r] = mnew[r];
        lacc[r] *= corr;
        #pragma unroll
        for (int nt = 0; nt < 4; nt++) oacc[nt][r] *= corr;
      }
    }

    // P -> LDS (transpose to PV A-operand layout)
    asm volatile("s_waitcnt lgkmcnt(0)" ::: "memory");  // WAR vs previous iter's reads
    #pragma unroll
    for (int g = 0; g < 4; g++)
      #pragma unroll
      for (int r = 0; r < 4; r++)
        p_lds[lg * 4 + r][g * 16 + lr] = f2bf(__expf(sg[g][r] - mrow[r]));
    asm volatile("s_waitcnt lgkmcnt(0)" ::: "memory");  // RAW: writes visible within wave

    __builtin_amdgcn_s_setprio(1);
    #pragma unroll
    for (int kc = 0; kc < 2; kc++) {
      s16x8 pa = *reinterpret_cast<const s16x8*>(&p_lds[lr][kc * 32 + lg * 8]);
      lacc = __builtin_amdgcn_mfma_f32_16x16x32_bf16(pa, ones, lacc, 0, 0, 0);  // row-sum
      #pragma unroll
      for (int nt = 0; nt < 4; nt++) {
        const int d = nt * 16 + lr;
        s16x8 vfr = *reinterpret_cast<const s16x8*>(
            &VT[c][d * 64 + (((kc * 4 + lg) ^ (d & 7)) * 8)]);
        oacc[nt] = __builtin_amdgcn_mfma_f32_16x16x32_bf16(pa, vfr, oacc[nt], 0, 0, 0);
      }
    }
    __builtin_amdgcn_s_setprio(0);

    __syncthreads();  // drains stage vmcnt + all LDS reads; flips buffers safely
  }

  #pragma unroll
  for (int nt = 0; nt < 4; nt++)
    #pragma unroll
    for (int r = 0; r < 4; r++) {
      float v = oacc[nt][r] / lacc[r];
      size_t tq = (size_t)(s_base + q0 + lg * 4 + r) * Bsz + b;
      ctx[tq * 512 + h * 64 + nt * 16 + lr] = f2bf(v);
    }
}

// ---------------- residual add (bf16 branches) + LayerNorm ----------------
template<int NADD>
__global__ void ln_kernel(const float* __restrict__ hin, const u16* __restrict__ a1,
                          const u16* __restrict__ a2, const float* __restrict__ gamma,
                          const float* __restrict__ beta, float* __restrict__ hf,
                          u16* __restrict__ hb) {
  int row = blockIdx.x * 4 + (threadIdx.x >> 6);
  int lane = threadIdx.x & 63;
  size_t base = (size_t)row * 512 + lane * 8;
  float4 h0 = *reinterpret_cast<const float4*>(hin + base);
  float4 h1 = *reinterpret_cast<const float4*>(hin + base + 4);
  s16x8 x1 = *reinterpret_cast<const s16x8*>(a1 + base);
  s16x8 x2 = {};
  if (NADD == 2) x2 = *reinterpret_cast<const s16x8*>(a2 + base);
  float v[8];
  float hv[8] = {h0.x, h0.y, h0.z, h0.w, h1.x, h1.y, h1.z, h1.w};
  float sum = 0.f;
  #pragma unroll
  for (int j = 0; j < 8; j++) {
    float t = hv[j] + bf2f((u16)x1[j]);
    if (NADD == 2) t += bf2f((u16)x2[j]);
    v[j] = t; sum += t;
  }
  #pragma unroll
  for (int o = 32; o >= 1; o >>= 1) sum += __shfl_xor(sum, o, 64);
  float mean = sum * (1.0f / 512.0f);
  float sq = 0.f;
  #pragma unroll
  for (int j = 0; j < 8; j++) { float d = v[j] - mean; sq += d * d; }
  #pragma unroll
  for (int o = 32; o >= 1; o >>= 1) sq += __shfl_xor(sq, o, 64);
  float rstd = rsqrtf(sq * (1.0f / 512.0f) + 1e-5f);
  #pragma unroll
  for (int j = 0; j < 8; j++) {
    int d = lane * 8 + j;
    float o = (v[j] - mean) * rstd * gamma[d] + beta[d];
    hf[base + j] = o;
    hb[base + j] = f2bf(o);
  }
}

// ---------------- final projection ----------------
__global__ void out_kernel(const float* __restrict__ hf, const float* __restrict__ Wout,
                           const float* __restrict__ bout, float* __restrict__ out) {
  int b = blockIdx.x; int lane = threadIdx.x;
  size_t base = ((size_t)(S - 1) * Bsz + b) * 512;
  float s = 0.f;
  #pragma unroll
  for (int j = 0; j < 8; j++) { int d = lane * 8 + j; s += hf[base + d] * Wout[d]; }
  #pragma unroll
  for (int o = 32; o >= 1; o >>= 1) s += __shfl_xor(s, o, 64);
  if (lane == 0) out[b] = s + bout[0];
}

extern "C" void kernel_launch(void* const* d_in, const int* in_sizes, int n_in,
                              void* d_out, int out_size, void* d_ws, size_t ws_size,
                              hipStream_t stream) {
  (void)in_sizes; (void)n_in; (void)out_size; (void)ws_size;
  const float* x      = (const float*)d_in[0];
  const float* W_emb  = (const float*)d_in[1];
  const float* b_emb  = (const float*)d_in[2];
  const float* Wqkv_g = (const float*)d_in[3];
  const float* bqkv_g = (const float*)d_in[4];
  const float* Wo_g   = (const float*)d_in[5];
  const float* bo_g   = (const float*)d_in[6];
  const float* Wqkv_l = (const float*)d_in[7];
  const float* bqkv_l = (const float*)d_in[8];
  const float* Wo_l   = (const float*)d_in[9];
  const float* bo_l   = (const float*)d_in[10];
  const float* W1     = (const float*)d_in[11];
  const float* b1f    = (const float*)d_in[12];
  const float* W2     = (const float*)d_in[13];
  const float* b2f    = (const float*)d_in[14];
  const float* g1     = (const float*)d_in[15];
  const float* be1    = (const float*)d_in[16];
  const float* g2     = (const float*)d_in[17];
  const float* be2    = (const float*)d_in[18];
  const float* W_out  = (const float*)d_in[19];
  const float* b_out  = (const float*)d_in[20];
  float* out = (float*)d_out;

  char* ws = (char*)d_ws;
  u16*   w_bf = (u16*)ws;                       // 32 MiB bf16 weights
  float* h_f  = (float*)(ws + 33554432);        // 32 MiB fp32 master
  u16*   h_b  = (u16*)(ws + 67108864);          // 16 MiB bf16 mirror
  u16*   qkv  = (u16*)(ws + 83886080);          // 48 MiB (dead after pack)
  u16*   q_pk = (u16*)(ws + 134217728);         // 16 MiB
  u16*   k_pk = (u16*)(ws + 150994944);         // 16 MiB
  u16*   v_pk = (u16*)(ws + 167772160);         // 16 MiB
  u16*   ctx  = (u16*)(ws + 83886080);          // 16 MiB, aliases dead qkv
  u16*   ff1  = (u16*)(ws + 83886080);          // 64 MiB, aliases dead qkv+q_pk
  u16*   go   = (u16*)(ws + 184549376);         // 16 MiB bf16 (also ff2)
  u16*   lo   = (u16*)(ws + 201326592);         // 16 MiB bf16 -> total 208 MiB

  u16* wqkvg = w_bf + 0;
  u16* wqkvl = w_bf + 3145728;
  u16* wog   = w_bf + 6291456;
  u16* wol   = w_bf + 7340032;
  u16* w1b   = w_bf + 8388608;
  u16* w2b   = w_bf + 12582912;

  auto cvt = [&](const float* s_, u16* d_, int n) {
    cvt_bf16_kernel<<<(n / 4 + 255) / 256, 256, 0, stream>>>(s_, d_, n / 4);
  };
  cvt(Wqkv_g, wqkvg, 3145728);
  cvt(Wqkv_l, wqkvl, 3145728);
  cvt(Wo_g,   wog,   1048576);
  cvt(Wo_l,   wol,   1048576);
  cvt(W1,     w1b,   4194304);
  cvt(W2,     w2b,   4194304);

  embed_kernel<<<T, 256, 0, stream>>>(x, W_emb, b_emb, h_f, h_b);

  for (int i = 0; i < Ln; i++) {
    // global attention
    gemm_bt_kernel<1><<<dim3(1536 / 128, T / 128), 256, 0, stream>>>(
        h_b, wqkvg + (size_t)i * 786432, bqkv_g + i * 1536, qkv, T, 1536, 512);
    pack_qkv_kernel<<<dim3(S / 64, Bsz, NHd), 256, 0, stream>>>(qkv, q_pk, k_pk, v_pk);
    flash_kernel<<<dim3(2048), 256, 0, stream>>>(q_pk, k_pk, v_pk, ctx, 2048, 32);
    gemm_bt_kernel<1><<<dim3(512 / 128, T / 128), 256, 0, stream>>>(
        ctx, wog + (size_t)i * 262144, bo_g + i * 512, go, T, 512, 512);
    // local (windowed) attention
    gemm_bt_kernel<1><<<dim3(1536 / 128, T / 128), 256, 0, stream>>>(
        h_b, wqkvl + (size_t)i * 786432, bqkv_l + i * 1536, qkv, T, 1536, 512);
    pack_qkv_kernel<<<dim3(S / 64, Bsz, NHd), 256, 0, stream>>>(qkv, q_pk, k_pk, v_pk);
    flash_kernel<<<dim3(2048), 256, 0, stream>>>(q_pk, k_pk, v_pk, ctx, 512, 8);
    gemm_bt_kernel<1><<<dim3(512 / 128, T / 128), 256, 0, stream>>>(
        ctx, wol + (size_t)i * 262144, bo_l + i * 512, lo, T, 512, 512);
    // LN1
    ln_kernel<2><<<T / 4, 256, 0, stream>>>(h_f, go, lo, g1 + i * 512, be1 + i * 512, h_f, h_b);
    // FFN
    gemm_bt_kernel<2><<<dim3(FFd / 128, T / 128), 256, 0, stream>>>(
        h_b, w1b + (size_t)i * 1048576, b1f + i * 2048, ff1, T, 2048, 512);
    gemm_bt_kernel<1><<<dim3(512 / 128, T / 128), 256, 0, stream>>>(
        ff1, w2b + (size_t)i * 1048576, b2f + i * 512, go, T, 512, 2048);
    ln_kernel<1><<<T / 4, 256, 0, stream>>>(h_f, go, nullptr, g2 + i * 512, be2 + i * 512, h_f, h_b);
  }

  out_kernel<<<Bsz, 64, 0, stream>>>(h_f, W_out, b_out, out);
}

// Round 5
// 1860.160 us; speedup vs baseline: 1.9968x; 1.1289x over previous
//
#include <hip/hip_runtime.h>
#include <hip/hip_bf16.h>

#define DEV __device__ __forceinline__

typedef __attribute__((ext_vector_type(4))) float f32x4;
typedef __attribute__((ext_vector_type(8))) short s16x8;
typedef unsigned short u16;

constexpr int Bsz = 8;      // batch
constexpr int S   = 2048;   // sequence
constexpr int Dm  = 512;    // model dim
constexpr int NHd = 8;      // heads
constexpr int FFd = 2048;
constexpr int Ln  = 4;
constexpr int T   = S * Bsz; // 16384 tokens

DEV u16 f2bf(float f) {
  union { float f; unsigned u; } v; v.f = f;
  unsigned r = v.u + 0x7fff + ((v.u >> 16) & 1);
  return (u16)(r >> 16);
}
DEV float bf2f(u16 a) { union { unsigned u; float f; } v; v.u = ((unsigned)a) << 16; return v.f; }
DEV float exp2g(float x) { return __builtin_amdgcn_exp2f(x); }   // v_exp_f32 (base-2 native)

typedef __attribute__((address_space(1))) const unsigned int guint;
typedef __attribute__((address_space(3))) unsigned int luint;
DEV void gload16(const void* g, void* l) {
  __builtin_amdgcn_global_load_lds((guint*)g, (luint*)l, 16, 0, 0);
}

// ---------------- weight fp32 -> bf16 ----------------
__global__ void cvt_bf16_kernel(const float* __restrict__ src, u16* __restrict__ dst, int n4) {
  int i = (blockIdx.x * 256 + threadIdx.x);
  if (i >= n4) return;
  float4 v = *reinterpret_cast<const float4*>(src + i * 4);
  ushort4 o; o.x = f2bf(v.x); o.y = f2bf(v.y); o.z = f2bf(v.z); o.w = f2bf(v.w);
  *reinterpret_cast<ushort4*>(dst + i * 4) = o;
}

// ---------------- embed + positional encoding ----------------
__global__ void embed_kernel(const float* __restrict__ x, const float* __restrict__ Wemb,
                             const float* __restrict__ bemb, float* __restrict__ hf,
                             u16* __restrict__ hb) {
  int t = blockIdx.x;            // token = s*B + b
  int s = t >> 3, b = t & 7;
  const float* xr = x + ((size_t)b * S + s) * 14;
  float xv[14];
  #pragma unroll
  for (int i = 0; i < 14; i++) xv[i] = xr[i];
  for (int d = threadIdx.x; d < Dm; d += blockDim.x) {
    const float* wr = Wemb + d * 14;
    float acc = bemb[d];
    #pragma unroll
    for (int i = 0; i < 14; i++) acc += xv[i] * wr[i];
    float ang = (float)s * expf((float)((d >> 1) * 2) * (-9.210340371976184f / 512.0f));
    acc += (d & 1) ? cosf(ang) : sinf(ang);
    hf[(size_t)t * Dm + d] = acc;
    hb[(size_t)t * Dm + d] = f2bf(acc);
  }
}

// ---------------- GEMM: C(M,N) = A(M,K) @ Bt(N,K)^T + bias ----------------
// OMODE: 0 = f32 out, 1 = bf16 out, 2 = bf16 out + relu
template<int OMODE>
__global__ __launch_bounds__(256, 2)
void gemm_bt_kernel(const u16* __restrict__ A, const u16* __restrict__ Bt,
                    const float* __restrict__ bias, void* __restrict__ Cout,
                    int M, int N, int K) {
  __shared__ __align__(16) u16 As[128 * 32];
  __shared__ __align__(16) u16 Bs[128 * 32];
  const int tid = threadIdx.x;
  const int lane = tid & 63, w = tid >> 6;
  const int wr = w >> 1, wc = w & 1;
  const int lr = lane & 15, lg = lane >> 4;
  const int m0 = blockIdx.y * 128, n0 = blockIdx.x * 128;

  f32x4 acc[4][4] = {};

  const int c1 = tid, c2 = tid + 256;
  const u16* gA1 = A + (size_t)(m0 + (c1 >> 2)) * K + (c1 & 3) * 8;
  const u16* gA2 = A + (size_t)(m0 + (c2 >> 2)) * K + (c2 & 3) * 8;
  const u16* gB1 = Bt + (size_t)(n0 + (c1 >> 2)) * K + (c1 & 3) * 8;
  const u16* gB2 = Bt + (size_t)(n0 + (c2 >> 2)) * K + (c2 & 3) * 8;
  u16* lA1 = As + c1 * 8; u16* lA2 = As + c2 * 8;
  u16* lB1 = Bs + c1 * 8; u16* lB2 = Bs + c2 * 8;

  for (int kt = 0; kt < K; kt += 32) {
    __syncthreads();
    gload16(gA1 + kt, lA1); gload16(gA2 + kt, lA2);
    gload16(gB1 + kt, lB1); gload16(gB2 + kt, lB2);
    __syncthreads();
    s16x8 a[4], bb[4];
    #pragma unroll
    for (int i = 0; i < 4; i++) {
      a[i]  = *reinterpret_cast<const s16x8*>(As + ((wr * 64 + i * 16 + lr) * 32 + lg * 8));
      bb[i] = *reinterpret_cast<const s16x8*>(Bs + ((wc * 64 + i * 16 + lr) * 32 + lg * 8));
    }
    #pragma unroll
    for (int mi = 0; mi < 4; mi++)
      #pragma unroll
      for (int ni = 0; ni < 4; ni++)
        acc[mi][ni] = __builtin_amdgcn_mfma_f32_16x16x32_bf16(a[mi], bb[ni], acc[mi][ni], 0, 0, 0);
  }

  #pragma unroll
  for (int mi = 0; mi < 4; mi++) {
    int row = m0 + wr * 64 + mi * 16 + lg * 4;
    #pragma unroll
    for (int ni = 0; ni < 4; ni++) {
      int col = n0 + wc * 64 + ni * 16 + lr;
      float bv = bias[col];
      #pragma unroll
      for (int r = 0; r < 4; r++) {
        float v = acc[mi][ni][r] + bv;
        if (OMODE == 2) v = v > 0.f ? v : 0.f;
        if (OMODE == 0) ((float*)Cout)[(size_t)(row + r) * N + col] = v;
        else            ((u16*)Cout)[(size_t)(row + r) * N + col] = f2bf(v);
      }
    }
  }
}

// ---------------- pack qkv -> per-(b,h) contiguous Q,K + transposed V ----------------
// q_pk[bh][s][64] (scaled by 0.125*log2e -> scores in log2 domain), k_pk[bh][s][64], v_pk[bh][64][S]
__global__ void pack_qkv_kernel(const u16* __restrict__ qkv, u16* __restrict__ q_pk,
                                u16* __restrict__ k_pk, u16* __restrict__ v_pk) {
  __shared__ u16 tile[64][66];
  int st = blockIdx.x, b = blockIdx.y, h = blockIdx.z;
  int tid = threadIdx.x;

  // V: stage 64x64 tile in LDS (rows = s), then write transposed
  #pragma unroll
  for (int p = 0; p < 4; p++) {
    int s = p * 16 + (tid >> 4);
    int dq = (tid & 15) * 4;
    size_t tok = (size_t)(st * 64 + s) * Bsz + b;
    ushort4 val = *reinterpret_cast<const ushort4*>(qkv + tok * 1536 + 1024 + h * 64 + dq);
    tile[s][dq] = val.x; tile[s][dq + 1] = val.y; tile[s][dq + 2] = val.z; tile[s][dq + 3] = val.w;
  }

  // Q (scaled) and K copies, coalesced 32B per thread
  {
    int s = tid >> 2, part = tid & 3;
    size_t tok = (size_t)(st * 64 + s) * Bsz + b;
    const u16* src = qkv + tok * 1536 + h * 64 + part * 16;
    size_t drow = ((size_t)(b * NHd + h) * S + st * 64 + s) * 64 + part * 16;
    s16x8 v0 = *reinterpret_cast<const s16x8*>(src);
    s16x8 v1 = *reinterpret_cast<const s16x8*>(src + 8);
    s16x8 o0, o1;
    const float qs = 0.18033688011112042f;   // 0.125 * log2(e)
    #pragma unroll
    for (int j = 0; j < 8; j++) {
      o0[j] = (short)f2bf(bf2f((u16)v0[j]) * qs);
      o1[j] = (short)f2bf(bf2f((u16)v1[j]) * qs);
    }
    *reinterpret_cast<s16x8*>(q_pk + drow) = o0;
    *reinterpret_cast<s16x8*>(q_pk + drow + 8) = o1;
    s16x8 k0 = *reinterpret_cast<const s16x8*>(src + 512);
    s16x8 k1 = *reinterpret_cast<const s16x8*>(src + 512 + 8);
    *reinterpret_cast<s16x8*>(k_pk + drow) = k0;
    *reinterpret_cast<s16x8*>(k_pk + drow + 8) = k1;
  }

  __syncthreads();
  #pragma unroll
  for (int p = 0; p < 4; p++) {
    int d = p * 16 + (tid >> 4);
    int s4 = (tid & 15) * 4;
    ushort4 o;
    o.x = tile[s4][d]; o.y = tile[s4 + 1][d]; o.z = tile[s4 + 2][d]; o.w = tile[s4 + 3][d];
    *reinterpret_cast<ushort4*>(v_pk + ((size_t)(b * NHd + h) * 64 + d) * S + st * 64 + s4) = o;
  }
}

// ---------------- flash attention v4: swapped QK^T (scores [k][q]) ----------------
// 1D grid, bid%8 = h (XCD pin); LDS-staged K/V (dbuf, XOR-swizzled, global_load_lds).
// mfma(K,Q) -> each lane holds 16 scores of ONE q-row (q=lr, k=g*16+lg*4+r):
//   - row-max: per-lane tree + 2 shuffles (xor 16,32) instead of 4-stage
//   - P pack: v_cvt_pk_bf16_f32 pairs + b64 write (r=0..3 are consecutive k)
//   - exp2 domain (Q pre-scaled by 0.125*log2e), defer-max THR=8 (T13)
__global__ __launch_bounds__(256, 3)
void flash_kernel(const u16* __restrict__ q_pk, const u16* __restrict__ k_pk,
                  const u16* __restrict__ v_pk, u16* __restrict__ ctx,
                  int S_att, int nqb) {
  const int tid = threadIdx.x;
  const int lane = tid & 63, w = tid >> 6;
  const int lr = lane & 15, lg = lane >> 4;
  const int bid = blockIdx.x;
  const int h = bid & 7;
  const int r_ = bid >> 3;
  const int qb = r_ % nqb;
  const int cw = r_ / nqb;
  const int b = cw & 7, n = cw >> 3;
  const int s_base = n * S_att;
  const int q0 = qb * 64 + w * 16;
  const int bh = b * NHd + h;

  __shared__ __align__(16) u16 KT[2][4096];   // [key 0..63][dk 0..63], seg-swizzled
  __shared__ __align__(16) u16 VT[2][4096];   // [d 0..63][k 0..63],    seg-swizzled
  __shared__ __align__(16) u16 p_lds_all[4][16][72];
  u16 (*p_lds)[72] = p_lds_all[w];

  const u16* qbase = q_pk + ((size_t)bh * S + s_base + q0) * 64;
  const u16* kbase = k_pk + ((size_t)bh * S + s_base) * 64;
  const u16* vbase = v_pk + (size_t)bh * 64 * S + s_base;

  s16x8 qf[2];
  qf[0] = *reinterpret_cast<const s16x8*>(qbase + (size_t)lr * 64 + lg * 8);
  qf[1] = *reinterpret_cast<const s16x8*>(qbase + (size_t)lr * 64 + lg * 8 + 32);

  s16x8 ones;
  #pragma unroll
  for (int j = 0; j < 8; j++) ones[j] = (short)0x3F80;  // bf16 1.0

  float mrow = -1e30f;                       // running max of q-row lr (log2 units)
  f32x4 lacc = (f32x4){0.f, 0.f, 0.f, 0.f};  // row-sum for rows lg*4+r
  f32x4 oacc[4];
  #pragma unroll
  for (int nt = 0; nt < 4; nt++) oacc[nt] = (f32x4){0.f, 0.f, 0.f, 0.f};

  // staging: thread t covers rows (t>>3) and (t>>3)+32, 16B segment (t&7),
  // global source pre-swizzled seg^=(row&7) so LDS dest stays linear (rule #21).
  const int seg = tid & 7, sr1 = tid >> 3, sr2 = (tid >> 3) + 32;
  const int ssw1 = (seg ^ (sr1 & 7)) * 8, ssw2 = (seg ^ (sr2 & 7)) * 8;

  auto stage = [&](int kb, int c) {
    const u16* kt = kbase + (size_t)kb * 64;
    gload16(kt + sr1 * 64 + ssw1, &KT[c][tid * 8]);
    gload16(kt + sr2 * 64 + ssw2, &KT[c][2048 + tid * 8]);
    const u16* vt = vbase + kb;
    gload16(vt + (size_t)sr1 * S + ssw1, &VT[c][tid * 8]);
    gload16(vt + (size_t)sr2 * S + ssw2, &VT[c][2048 + tid * 8]);
  };

  stage(0, 0);
  __syncthreads();

  for (int kb = 0; kb < S_att; kb += 64) {
    const int c = (kb >> 6) & 1;
    if (kb + 64 < S_att) stage(kb + 64, c ^ 1);   // prefetch: drains at end-of-iter barrier

    // K^T Q: rows = keys, cols = q. Same operand reads as before, swapped in the mfma.
    f32x4 sg[4];
    __builtin_amdgcn_s_setprio(1);
    #pragma unroll
    for (int g = 0; g < 4; g++) {
      const int key = g * 16 + lr, kw = key & 7;
      const u16* kp = &KT[c][key * 64];
      s16x8 k0 = *reinterpret_cast<const s16x8*>(kp + ((lg ^ kw) * 8));
      s16x8 k1 = *reinterpret_cast<const s16x8*>(kp + (((4 + lg) ^ kw) * 8));
      f32x4 sc = (f32x4){0.f, 0.f, 0.f, 0.f};
      sc = __builtin_amdgcn_mfma_f32_16x16x32_bf16(k0, qf[0], sc, 0, 0, 0);
      sc = __builtin_amdgcn_mfma_f32_16x16x32_bf16(k1, qf[1], sc, 0, 0, 0);
      sg[g] = sc;   // sg[g][r] = score(k = kb + g*16 + lg*4 + r, q = lr)
    }
    __builtin_amdgcn_s_setprio(0);

    // tile max of q-row lr: per-lane tree over 16, then reduce across lg (xor 16,32)
    float t0 = fmaxf(fmaxf(sg[0][0], sg[0][1]), fmaxf(sg[0][2], sg[0][3]));
    float t1 = fmaxf(fmaxf(sg[1][0], sg[1][1]), fmaxf(sg[1][2], sg[1][3]));
    float t2 = fmaxf(fmaxf(sg[2][0], sg[2][1]), fmaxf(sg[2][2], sg[2][3]));
    float t3 = fmaxf(fmaxf(sg[3][0], sg[3][1]), fmaxf(sg[3][2], sg[3][3]));
    float tmax = fmaxf(fmaxf(t0, t1), fmaxf(t2, t3));
    tmax = fmaxf(tmax, __shfl_xor(tmax, 16, 64));
    tmax = fmaxf(tmax, __shfl_xor(tmax, 32, 64));

    // defer-max (T13): only rescale when some row grew by > 8 (log2 units; P <= 2^8)
    if (__any((int)(tmax > mrow + 8.f))) {
      float mnew = fmaxf(mrow, tmax);
      float cf = exp2g(mrow - mnew);   // correction for q-row lr
      mrow = mnew;
      #pragma unroll
      for (int r = 0; r < 4; r++) {
        float co = __shfl(cf, lg * 4 + r, 16);   // correction for q-row lg*4+r
        lacc[r] *= co;
        #pragma unroll
        for (int nt = 0; nt < 4; nt++) oacc[nt][r] *= co;
      }
    }

    // P -> LDS: exp2, pack pairs with v_cvt_pk_bf16_f32, b64 write (4 consecutive k)
    asm volatile("s_waitcnt lgkmcnt(0)" ::: "memory");  // WAR vs previous iter's reads
    #pragma unroll
    for (int g = 0; g < 4; g++) {
      float e0 = exp2g(sg[g][0] - mrow);
      float e1 = exp2g(sg[g][1] - mrow);
      float e2 = exp2g(sg[g][2] - mrow);
      float e3 = exp2g(sg[g][3] - mrow);
      unsigned p01, p23;
      asm("v_cvt_pk_bf16_f32 %0, %1, %2" : "=v"(p01) : "v"(e0), "v"(e1));
      asm("v_cvt_pk_bf16_f32 %0, %1, %2" : "=v"(p23) : "v"(e2), "v"(e3));
      uint2 pk; pk.x = p01; pk.y = p23;
      *reinterpret_cast<uint2*>(&p_lds[lr][g * 16 + lg * 4]) = pk;
    }
    asm volatile("s_waitcnt lgkmcnt(0)" ::: "memory");  // RAW: writes visible within wave

    __builtin_amdgcn_s_setprio(1);
    #pragma unroll
    for (int kc = 0; kc < 2; kc++) {
      s16x8 pa = *reinterpret_cast<const s16x8*>(&p_lds[lr][kc * 32 + lg * 8]);
      lacc = __builtin_amdgcn_mfma_f32_16x16x32_bf16(pa, ones, lacc, 0, 0, 0);  // row-sum
      #pragma unroll
      for (int nt = 0; nt < 4; nt++) {
        const int d = nt * 16 + lr;
        s16x8 vfr = *reinterpret_cast<const s16x8*>(
            &VT[c][d * 64 + (((kc * 4 + lg) ^ (d & 7)) * 8)]);
        oacc[nt] = __builtin_amdgcn_mfma_f32_16x16x32_bf16(pa, vfr, oacc[nt], 0, 0, 0);
      }
    }
    __builtin_amdgcn_s_setprio(0);

    __syncthreads();  // drains stage vmcnt + all LDS reads; flips buffers safely
  }

  #pragma unroll
  for (int nt = 0; nt < 4; nt++)
    #pragma unroll
    for (int r = 0; r < 4; r++) {
      float v = oacc[nt][r] / lacc[r];
      size_t tq = (size_t)(s_base + q0 + lg * 4 + r) * Bsz + b;
      ctx[tq * 512 + h * 64 + nt * 16 + lr] = f2bf(v);
    }
}

// ---------------- residual add (bf16 branches) + LayerNorm ----------------
template<int NADD>
__global__ void ln_kernel(const float* __restrict__ hin, const u16* __restrict__ a1,
                          const u16* __restrict__ a2, const float* __restrict__ gamma,
                          const float* __restrict__ beta, float* __restrict__ hf,
                          u16* __restrict__ hb) {
  int row = blockIdx.x * 4 + (threadIdx.x >> 6);
  int lane = threadIdx.x & 63;
  size_t base = (size_t)row * 512 + lane * 8;
  float4 h0 = *reinterpret_cast<const float4*>(hin + base);
  float4 h1 = *reinterpret_cast<const float4*>(hin + base + 4);
  s16x8 x1 = *reinterpret_cast<const s16x8*>(a1 + base);
  s16x8 x2 = {};
  if (NADD == 2) x2 = *reinterpret_cast<const s16x8*>(a2 + base);
  float v[8];
  float hv[8] = {h0.x, h0.y, h0.z, h0.w, h1.x, h1.y, h1.z, h1.w};
  float sum = 0.f;
  #pragma unroll
  for (int j = 0; j < 8; j++) {
    float t = hv[j] + bf2f((u16)x1[j]);
    if (NADD == 2) t += bf2f((u16)x2[j]);
    v[j] = t; sum += t;
  }
  #pragma unroll
  for (int o = 32; o >= 1; o >>= 1) sum += __shfl_xor(sum, o, 64);
  float mean = sum * (1.0f / 512.0f);
  float sq = 0.f;
  #pragma unroll
  for (int j = 0; j < 8; j++) { float d = v[j] - mean; sq += d * d; }
  #pragma unroll
  for (int o = 32; o >= 1; o >>= 1) sq += __shfl_xor(sq, o, 64);
  float rstd = rsqrtf(sq * (1.0f / 512.0f) + 1e-5f);
  #pragma unroll
  for (int j = 0; j < 8; j++) {
    int d = lane * 8 + j;
    float o = (v[j] - mean) * rstd * gamma[d] + beta[d];
    hf[base + j] = o;
    hb[base + j] = f2bf(o);
  }
}

// ---------------- final projection ----------------
__global__ void out_kernel(const float* __restrict__ hf, const float* __restrict__ Wout,
                           const float* __restrict__ bout, float* __restrict__ out) {
  int b = blockIdx.x; int lane = threadIdx.x;
  size_t base = ((size_t)(S - 1) * Bsz + b) * 512;
  float s = 0.f;
  #pragma unroll
  for (int j = 0; j < 8; j++) { int d = lane * 8 + j; s += hf[base + d] * Wout[d]; }
  #pragma unroll
  for (int o = 32; o >= 1; o >>= 1) s += __shfl_xor(s, o, 64);
  if (lane == 0) out[b] = s + bout[0];
}

extern "C" void kernel_launch(void* const* d_in, const int* in_sizes, int n_in,
                              void* d_out, int out_size, void* d_ws, size_t ws_size,
                              hipStream_t stream) {
  (void)in_sizes; (void)n_in; (void)out_size; (void)ws_size;
  const float* x      = (const float*)d_in[0];
  const float* W_emb  = (const float*)d_in[1];
  const float* b_emb  = (const float*)d_in[2];
  const float* Wqkv_g = (const float*)d_in[3];
  const float* bqkv_g = (const float*)d_in[4];
  const float* Wo_g   = (const float*)d_in[5];
  const float* bo_g   = (const float*)d_in[6];
  const float* Wqkv_l = (const float*)d_in[7];
  const float* bqkv_l = (const float*)d_in[8];
  const float* Wo_l   = (const float*)d_in[9];
  const float* bo_l   = (const float*)d_in[10];
  const float* W1     = (const float*)d_in[11];
  const float* b1f    = (const float*)d_in[12];
  const float* W2     = (const float*)d_in[13];
  const float* b2f    = (const float*)d_in[14];
  const float* g1     = (const float*)d_in[15];
  const float* be1    = (const float*)d_in[16];
  const float* g2     = (const float*)d_in[17];
  const float* be2    = (const float*)d_in[18];
  const float* W_out  = (const float*)d_in[19];
  const float* b_out  = (const float*)d_in[20];
  float* out = (float*)d_out;

  char* ws = (char*)d_ws;
  u16*   w_bf = (u16*)ws;                       // 32 MiB bf16 weights
  float* h_f  = (float*)(ws + 33554432);        // 32 MiB fp32 master
  u16*   h_b  = (u16*)(ws + 67108864);          // 16 MiB bf16 mirror
  u16*   qkv  = (u16*)(ws + 83886080);          // 48 MiB (dead after pack)
  u16*   q_pk = (u16*)(ws + 134217728);         // 16 MiB
  u16*   k_pk = (u16*)(ws + 150994944);         // 16 MiB
  u16*   v_pk = (u16*)(ws + 167772160);         // 16 MiB
  u16*   ctx  = (u16*)(ws + 83886080);          // 16 MiB, aliases dead qkv
  u16*   ff1  = (u16*)(ws + 83886080);          // 64 MiB, aliases dead qkv+q_pk
  u16*   go   = (u16*)(ws + 184549376);         // 16 MiB bf16 (also ff2)
  u16*   lo   = (u16*)(ws + 201326592);         // 16 MiB bf16 -> total 208 MiB

  u16* wqkvg = w_bf + 0;
  u16* wqkvl = w_bf + 3145728;
  u16* wog   = w_bf + 6291456;
  u16* wol   = w_bf + 7340032;
  u16* w1b   = w_bf + 8388608;
  u16* w2b   = w_bf + 12582912;

  auto cvt = [&](const float* s_, u16* d_, int n) {
    cvt_bf16_kernel<<<(n / 4 + 255) / 256, 256, 0, stream>>>(s_, d_, n / 4);
  };
  cvt(Wqkv_g, wqkvg, 3145728);
  cvt(Wqkv_l, wqkvl, 3145728);
  cvt(Wo_g,   wog,   1048576);
  cvt(Wo_l,   wol,   1048576);
  cvt(W1,     w1b,   4194304);
  cvt(W2,     w2b,   4194304);

  embed_kernel<<<T, 256, 0, stream>>>(x, W_emb, b_emb, h_f, h_b);

  for (int i = 0; i < Ln; i++) {
    // global attention
    gemm_bt_kernel<1><<<dim3(1536 / 128, T / 128), 256, 0, stream>>>(
        h_b, wqkvg + (size_t)i * 786432, bqkv_g + i * 1536, qkv, T, 1536, 512);
    pack_qkv_kernel<<<dim3(S / 64, Bsz, NHd), 256, 0, stream>>>(qkv, q_pk, k_pk, v_pk);
    flash_kernel<<<dim3(2048), 256, 0, stream>>>(q_pk, k_pk, v_pk, ctx, 2048, 32);
    gemm_bt_kernel<1><<<dim3(512 / 128, T / 128), 256, 0, stream>>>(
        ctx, wog + (size_t)i * 262144, bo_g + i * 512, go, T, 512, 512);
    // local (windowed) attention
    gemm_bt_kernel<1><<<dim3(1536 / 128, T / 128), 256, 0, stream>>>(
        h_b, wqkvl + (size_t)i * 786432, bqkv_l + i * 1536, qkv, T, 1536, 512);
    pack_qkv_kernel<<<dim3(S / 64, Bsz, NHd), 256, 0, stream>>>(qkv, q_pk, k_pk, v_pk);
    flash_kernel<<<dim3(2048), 256, 0, stream>>>(q_pk, k_pk, v_pk, ctx, 512, 8);
    gemm_bt_kernel<1><<<dim3(512 / 128, T / 128), 256, 0, stream>>>(
        ctx, wol + (size_t)i * 262144, bo_l + i * 512, lo, T, 512, 512);
    // LN1
    ln_kernel<2><<<T / 4, 256, 0, stream>>>(h_f, go, lo, g1 + i * 512, be1 + i * 512, h_f, h_b);
    // FFN
    gemm_bt_kernel<2><<<dim3(FFd / 128, T / 128), 256, 0, stream>>>(
        h_b, w1b + (size_t)i * 1048576, b1f + i * 2048, ff1, T, 2048, 512);
    gemm_bt_kernel<1><<<dim3(512 / 128, T / 128), 256, 0, stream>>>(
        ff1, w2b + (size_t)i * 1048576, b2f + i * 512, go, T, 512, 2048);
    ln_kernel<1><<<T / 4, 256, 0, stream>>>(h_f, go, nullptr, g2 + i * 512, be2 + i * 512, h_f, h_b);
  }

  out_kernel<<<Bsz, 64, 0, stream>>>(h_f, W_out, b_out, out);
}

// Round 6
// 1815.369 us; speedup vs baseline: 2.0460x; 1.0247x over previous
//
#include <hip/hip_runtime.h>
#include <hip/hip_bf16.h>

#define DEV __device__ __forceinline__

typedef __attribute__((ext_vector_type(4))) float f32x4;
typedef __attribute__((ext_vector_type(8))) short s16x8;
typedef unsigned short u16;

constexpr int Bsz = 8;      // batch
constexpr int S   = 2048;   // sequence
constexpr int Dm  = 512;    // model dim
constexpr int NHd = 8;      // heads
constexpr int FFd = 2048;
constexpr int Ln  = 4;
constexpr int T   = S * Bsz; // 16384 tokens; token index t = b*S + s (batch-major)

DEV u16 f2bf(float f) {
  union { float f; unsigned u; } v; v.f = f;
  unsigned r = v.u + 0x7fff + ((v.u >> 16) & 1);
  return (u16)(r >> 16);
}
DEV float bf2f(u16 a) { union { unsigned u; float f; } v; v.u = ((unsigned)a) << 16; return v.f; }
DEV float exp2g(float x) { return __builtin_amdgcn_exp2f(x); }   // v_exp_f32 (base-2 native)

typedef __attribute__((address_space(1))) const unsigned int guint;
typedef __attribute__((address_space(3))) unsigned int luint;
DEV void gload16(const void* g, void* l) {
  __builtin_amdgcn_global_load_lds((guint*)g, (luint*)l, 16, 0, 0);
}

// ---------------- weight fp32 -> bf16 ----------------
__global__ void cvt_bf16_kernel(const float* __restrict__ src, u16* __restrict__ dst, int n4) {
  int i = (blockIdx.x * 256 + threadIdx.x);
  if (i >= n4) return;
  float4 v = *reinterpret_cast<const float4*>(src + i * 4);
  ushort4 o; o.x = f2bf(v.x); o.y = f2bf(v.y); o.z = f2bf(v.z); o.w = f2bf(v.w);
  *reinterpret_cast<ushort4*>(dst + i * 4) = o;
}

// ---------------- embed + positional encoding (token t = b*S + s) ----------------
__global__ void embed_kernel(const float* __restrict__ x, const float* __restrict__ Wemb,
                             const float* __restrict__ bemb, float* __restrict__ hf,
                             u16* __restrict__ hb) {
  int t = blockIdx.x;
  int b = t >> 11, s = t & 2047;
  const float* xr = x + ((size_t)b * S + s) * 14;
  float xv[14];
  #pragma unroll
  for (int i = 0; i < 14; i++) xv[i] = xr[i];
  for (int d = threadIdx.x; d < Dm; d += blockDim.x) {
    const float* wr = Wemb + d * 14;
    float acc = bemb[d];
    #pragma unroll
    for (int i = 0; i < 14; i++) acc += xv[i] * wr[i];
    float ang = (float)s * expf((float)((d >> 1) * 2) * (-9.210340371976184f / 512.0f));
    acc += (d & 1) ? cosf(ang) : sinf(ang);
    hf[(size_t)t * Dm + d] = acc;
    hb[(size_t)t * Dm + d] = f2bf(acc);
  }
}

// ---------------- GEMM: C(M,N) = A(M,K) @ Bt(N,K)^T + bias ----------------
// Double-buffered LDS, counted vmcnt(4) + raw barriers (T3/T4-minimum):
// prefetch of tile t+1 stays in flight across the barrier; never drain to 0 mid-loop.
// OMODE: 0 = f32 out, 1 = bf16 out, 2 = bf16 out + relu
template<int OMODE>
__global__ __launch_bounds__(256, 2)
void gemm_bt_kernel(const u16* __restrict__ A, const u16* __restrict__ Bt,
                    const float* __restrict__ bias, void* __restrict__ Cout,
                    int M, int N, int K) {
  __shared__ __align__(16) u16 As[2][128 * 32];
  __shared__ __align__(16) u16 Bs[2][128 * 32];
  const int tid = threadIdx.x;
  const int lane = tid & 63, w = tid >> 6;
  const int wr = w >> 1, wc = w & 1;
  const int lr = lane & 15, lg = lane >> 4;
  const int m0 = blockIdx.y * 128, n0 = blockIdx.x * 128;

  f32x4 acc[4][4] = {};

  const int c1 = tid, c2 = tid + 256;
  const u16* gA1 = A + (size_t)(m0 + (c1 >> 2)) * K + (c1 & 3) * 8;
  const u16* gA2 = A + (size_t)(m0 + (c2 >> 2)) * K + (c2 & 3) * 8;
  const u16* gB1 = Bt + (size_t)(n0 + (c1 >> 2)) * K + (c1 & 3) * 8;
  const u16* gB2 = Bt + (size_t)(n0 + (c2 >> 2)) * K + (c2 & 3) * 8;

  const int nk = K >> 5;
  auto stage = [&](int t, int c) {
    const int kt = t * 32;
    gload16(gA1 + kt, As[c] + c1 * 8); gload16(gA2 + kt, As[c] + c2 * 8);
    gload16(gB1 + kt, Bs[c] + c1 * 8); gload16(gB2 + kt, Bs[c] + c2 * 8);
  };

  stage(0, 0);
  for (int t = 0; t < nk; ++t) {
    const int c = t & 1;
    if (t + 1 < nk) {
      stage(t + 1, c ^ 1);                                // 4 more loads in flight
      asm volatile("s_waitcnt vmcnt(4)" ::: "memory");    // buf c landed (mine)
    } else {
      asm volatile("s_waitcnt vmcnt(0)" ::: "memory");
    }
    __builtin_amdgcn_s_barrier();                         // everyone's buf c landed

    s16x8 a[4], bb[4];
    #pragma unroll
    for (int i = 0; i < 4; i++) {
      a[i]  = *reinterpret_cast<const s16x8*>(As[c] + ((wr * 64 + i * 16 + lr) * 32 + lg * 8));
      bb[i] = *reinterpret_cast<const s16x8*>(Bs[c] + ((wc * 64 + i * 16 + lr) * 32 + lg * 8));
    }
    #pragma unroll
    for (int mi = 0; mi < 4; mi++)
      #pragma unroll
      for (int ni = 0; ni < 4; ni++)
        acc[mi][ni] = __builtin_amdgcn_mfma_f32_16x16x32_bf16(a[mi], bb[ni], acc[mi][ni], 0, 0, 0);

    __builtin_amdgcn_s_barrier();   // WAR: all reads of buf c done before next stage overwrites
  }

  #pragma unroll
  for (int mi = 0; mi < 4; mi++) {
    int row = m0 + wr * 64 + mi * 16 + lg * 4;
    #pragma unroll
    for (int ni = 0; ni < 4; ni++) {
      int col = n0 + wc * 64 + ni * 16 + lr;
      float bv = bias[col];
      #pragma unroll
      for (int r = 0; r < 4; r++) {
        float v = acc[mi][ni][r] + bv;
        if (OMODE == 2) v = v > 0.f ? v : 0.f;
        if (OMODE == 0) ((float*)Cout)[(size_t)(row + r) * N + col] = v;
        else            ((u16*)Cout)[(size_t)(row + r) * N + col] = f2bf(v);
      }
    }
  }
}

// ---------------- V-only pack: v_pk[bh][d][s] from qkv[(b*S+s)][1024+h*64+d] ----------------
__global__ void packv_kernel(const u16* __restrict__ qkv, u16* __restrict__ v_pk) {
  __shared__ u16 tile[64][66];
  int st = blockIdx.x, b = blockIdx.y, h = blockIdx.z;
  int tid = threadIdx.x;
  #pragma unroll
  for (int p = 0; p < 4; p++) {
    int s = p * 16 + (tid >> 4);
    int dq = (tid & 15) * 4;
    size_t tok = (size_t)b * S + st * 64 + s;
    ushort4 val = *reinterpret_cast<const ushort4*>(qkv + tok * 1536 + 1024 + h * 64 + dq);
    tile[s][dq] = val.x; tile[s][dq + 1] = val.y; tile[s][dq + 2] = val.z; tile[s][dq + 3] = val.w;
  }
  __syncthreads();
  #pragma unroll
  for (int p = 0; p < 4; p++) {
    int d = p * 16 + (tid >> 4);
    int s4 = (tid & 15) * 4;
    ushort4 o;
    o.x = tile[s4][d]; o.y = tile[s4 + 1][d]; o.z = tile[s4 + 2][d]; o.w = tile[s4 + 3][d];
    *reinterpret_cast<ushort4*>(v_pk + ((size_t)(b * NHd + h) * 64 + d) * S + st * 64 + s4) = o;
  }
}

// ---------------- flash attention v5: Q/K direct from qkv (batch-major tokens) ----------------
// 1D grid, bid%8 = h (XCD pin); K staged from qkv rows (128B/row contiguous), V from v_pk.
// Swapped mfma(K,Q): lane holds 16 scores of one q-row; exp2 domain; defer-max THR=8.
__global__ __launch_bounds__(256, 3)
void flash_kernel(const u16* __restrict__ qkv, const u16* __restrict__ v_pk,
                  u16* __restrict__ ctx, int S_att, int nqb) {
  const int tid = threadIdx.x;
  const int lane = tid & 63, w = tid >> 6;
  const int lr = lane & 15, lg = lane >> 4;
  const int bid = blockIdx.x;
  const int h = bid & 7;
  const int r_ = bid >> 3;
  const int qb = r_ % nqb;
  const int cw = r_ / nqb;
  const int b = cw & 7, n = cw >> 3;
  const int s_base = n * S_att;
  const int q0 = qb * 64 + w * 16;

  __shared__ __align__(16) u16 KT[2][4096];   // [key 0..63][dk 0..63], seg-swizzled
  __shared__ __align__(16) u16 VT[2][4096];   // [d 0..63][k 0..63],    seg-swizzled
  __shared__ __align__(16) u16 p_lds_all[4][16][72];
  u16 (*p_lds)[72] = p_lds_all[w];

  const u16* vbase = v_pk + (size_t)(b * NHd + h) * 64 * S + s_base;

  // Q direct load + scale (0.125 * log2e) + repack to bf16
  s16x8 qf[2];
  {
    const u16* qp = qkv + ((size_t)b * S + s_base + q0 + lr) * 1536 + h * 64 + lg * 8;
    s16x8 r0 = *reinterpret_cast<const s16x8*>(qp);
    s16x8 r1 = *reinterpret_cast<const s16x8*>(qp + 32);
    const float qs = 0.18033688011112042f;
    #pragma unroll
    for (int j = 0; j < 8; j++) {
      qf[0][j] = (short)f2bf(bf2f((u16)r0[j]) * qs);
      qf[1][j] = (short)f2bf(bf2f((u16)r1[j]) * qs);
    }
  }

  s16x8 ones;
  #pragma unroll
  for (int j = 0; j < 8; j++) ones[j] = (short)0x3F80;  // bf16 1.0

  float mrow = -1e30f;                       // running max of q-row lr (log2 units)
  f32x4 lacc = (f32x4){0.f, 0.f, 0.f, 0.f};  // row-sum for rows lg*4+r
  f32x4 oacc[4];
  #pragma unroll
  for (int nt = 0; nt < 4; nt++) oacc[nt] = (f32x4){0.f, 0.f, 0.f, 0.f};

  // staging: thread t covers rows (t>>3) and (t>>3)+32, 16B segment (t&7),
  // global source pre-swizzled seg^=(row&7), LDS dest linear (rule #21).
  const int seg = tid & 7, sr1 = tid >> 3, sr2 = (tid >> 3) + 32;
  const int ssw1 = (seg ^ (sr1 & 7)) * 8, ssw2 = (seg ^ (sr2 & 7)) * 8;

  const u16* kroot = qkv + ((size_t)b * S + s_base) * 1536 + 512 + h * 64;

  auto stage = [&](int kb, int c) {
    const u16* kt = kroot + (size_t)kb * 1536;
    gload16(kt + (size_t)sr1 * 1536 + ssw1, &KT[c][tid * 8]);
    gload16(kt + (size_t)sr2 * 1536 + ssw2, &KT[c][2048 + tid * 8]);
    const u16* vt = vbase + kb;
    gload16(vt + (size_t)sr1 * S + ssw1, &VT[c][tid * 8]);
    gload16(vt + (size_t)sr2 * S + ssw2, &VT[c][2048 + tid * 8]);
  };

  stage(0, 0);
  __syncthreads();

  for (int kb = 0; kb < S_att; kb += 64) {
    const int c = (kb >> 6) & 1;
    if (kb + 64 < S_att) stage(kb + 64, c ^ 1);   // prefetch: drains at end-of-iter barrier

    // K^T Q: rows = keys, cols = q
    f32x4 sg[4];
    __builtin_amdgcn_s_setprio(1);
    #pragma unroll
    for (int g = 0; g < 4; g++) {
      const int key = g * 16 + lr, kw = key & 7;
      const u16* kp = &KT[c][key * 64];
      s16x8 k0 = *reinterpret_cast<const s16x8*>(kp + ((lg ^ kw) * 8));
      s16x8 k1 = *reinterpret_cast<const s16x8*>(kp + (((4 + lg) ^ kw) * 8));
      f32x4 sc = (f32x4){0.f, 0.f, 0.f, 0.f};
      sc = __builtin_amdgcn_mfma_f32_16x16x32_bf16(k0, qf[0], sc, 0, 0, 0);
      sc = __builtin_amdgcn_mfma_f32_16x16x32_bf16(k1, qf[1], sc, 0, 0, 0);
      sg[g] = sc;   // sg[g][r] = score(k = kb + g*16 + lg*4 + r, q = lr)
    }
    __builtin_amdgcn_s_setprio(0);

    // tile max of q-row lr: per-lane tree, then reduce across lg (xor 16,32)
    float t0 = fmaxf(fmaxf(sg[0][0], sg[0][1]), fmaxf(sg[0][2], sg[0][3]));
    float t1 = fmaxf(fmaxf(sg[1][0], sg[1][1]), fmaxf(sg[1][2], sg[1][3]));
    float t2 = fmaxf(fmaxf(sg[2][0], sg[2][1]), fmaxf(sg[2][2], sg[2][3]));
    float t3 = fmaxf(fmaxf(sg[3][0], sg[3][1]), fmaxf(sg[3][2], sg[3][3]));
    float tmax = fmaxf(fmaxf(t0, t1), fmaxf(t2, t3));
    tmax = fmaxf(tmax, __shfl_xor(tmax, 16, 64));
    tmax = fmaxf(tmax, __shfl_xor(tmax, 32, 64));

    // defer-max (T13): only rescale when some row grew by > 8 (log2 units; P <= 2^8)
    if (__any((int)(tmax > mrow + 8.f))) {
      float mnew = fmaxf(mrow, tmax);
      float cf = exp2g(mrow - mnew);   // correction for q-row lr
      mrow = mnew;
      #pragma unroll
      for (int r = 0; r < 4; r++) {
        float co = __shfl(cf, lg * 4 + r, 16);   // correction for q-row lg*4+r
        lacc[r] *= co;
        #pragma unroll
        for (int nt = 0; nt < 4; nt++) oacc[nt][r] *= co;
      }
    }

    // P -> LDS: exp2, pack pairs with v_cvt_pk_bf16_f32, b64 write (4 consecutive k)
    asm volatile("s_waitcnt lgkmcnt(0)" ::: "memory");  // WAR vs previous iter's reads
    #pragma unroll
    for (int g = 0; g < 4; g++) {
      float e0 = exp2g(sg[g][0] - mrow);
      float e1 = exp2g(sg[g][1] - mrow);
      float e2 = exp2g(sg[g][2] - mrow);
      float e3 = exp2g(sg[g][3] - mrow);
      unsigned p01, p23;
      asm("v_cvt_pk_bf16_f32 %0, %1, %2" : "=v"(p01) : "v"(e0), "v"(e1));
      asm("v_cvt_pk_bf16_f32 %0, %1, %2" : "=v"(p23) : "v"(e2), "v"(e3));
      uint2 pk; pk.x = p01; pk.y = p23;
      *reinterpret_cast<uint2*>(&p_lds[lr][g * 16 + lg * 4]) = pk;
    }
    asm volatile("s_waitcnt lgkmcnt(0)" ::: "memory");  // RAW: writes visible within wave

    __builtin_amdgcn_s_setprio(1);
    #pragma unroll
    for (int kc = 0; kc < 2; kc++) {
      s16x8 pa = *reinterpret_cast<const s16x8*>(&p_lds[lr][kc * 32 + lg * 8]);
      lacc = __builtin_amdgcn_mfma_f32_16x16x32_bf16(pa, ones, lacc, 0, 0, 0);  // row-sum
      #pragma unroll
      for (int nt = 0; nt < 4; nt++) {
        const int d = nt * 16 + lr;
        s16x8 vfr = *reinterpret_cast<const s16x8*>(
            &VT[c][d * 64 + (((kc * 4 + lg) ^ (d & 7)) * 8)]);
        oacc[nt] = __builtin_amdgcn_mfma_f32_16x16x32_bf16(pa, vfr, oacc[nt], 0, 0, 0);
      }
    }
    __builtin_amdgcn_s_setprio(0);

    __syncthreads();  // drains stage vmcnt + all LDS reads; flips buffers safely
  }

  #pragma unroll
  for (int nt = 0; nt < 4; nt++)
    #pragma unroll
    for (int r = 0; r < 4; r++) {
      float v = oacc[nt][r] / lacc[r];
      size_t tq = (size_t)b * S + s_base + q0 + lg * 4 + r;
      ctx[tq * 512 + h * 64 + nt * 16 + lr] = f2bf(v);
    }
}

// ---------------- residual add (bf16 branches) + LayerNorm ----------------
template<int NADD>
__global__ void ln_kernel(const float* __restrict__ hin, const u16* __restrict__ a1,
                          const u16* __restrict__ a2, const float* __restrict__ gamma,
                          const float* __restrict__ beta, float* __restrict__ hf,
                          u16* __restrict__ hb) {
  int row = blockIdx.x * 4 + (threadIdx.x >> 6);
  int lane = threadIdx.x & 63;
  size_t base = (size_t)row * 512 + lane * 8;
  float4 h0 = *reinterpret_cast<const float4*>(hin + base);
  float4 h1 = *reinterpret_cast<const float4*>(hin + base + 4);
  s16x8 x1 = *reinterpret_cast<const s16x8*>(a1 + base);
  s16x8 x2 = {};
  if (NADD == 2) x2 = *reinterpret_cast<const s16x8*>(a2 + base);
  float v[8];
  float hv[8] = {h0.x, h0.y, h0.z, h0.w, h1.x, h1.y, h1.z, h1.w};
  float sum = 0.f;
  #pragma unroll
  for (int j = 0; j < 8; j++) {
    float t = hv[j] + bf2f((u16)x1[j]);
    if (NADD == 2) t += bf2f((u16)x2[j]);
    v[j] = t; sum += t;
  }
  #pragma unroll
  for (int o = 32; o >= 1; o >>= 1) sum += __shfl_xor(sum, o, 64);
  float mean = sum * (1.0f / 512.0f);
  float sq = 0.f;
  #pragma unroll
  for (int j = 0; j < 8; j++) { float d = v[j] - mean; sq += d * d; }
  #pragma unroll
  for (int o = 32; o >= 1; o >>= 1) sq += __shfl_xor(sq, o, 64);
  float rstd = rsqrtf(sq * (1.0f / 512.0f) + 1e-5f);
  #pragma unroll
  for (int j = 0; j < 8; j++) {
    int d = lane * 8 + j;
    float o = (v[j] - mean) * rstd * gamma[d] + beta[d];
    hf[base + j] = o;
    hb[base + j] = f2bf(o);
  }
}

// ---------------- final projection (token (s=S-1, b) = b*S + S-1) ----------------
__global__ void out_kernel(const float* __restrict__ hf, const float* __restrict__ Wout,
                           const float* __restrict__ bout, float* __restrict__ out) {
  int b = blockIdx.x; int lane = threadIdx.x;
  size_t base = ((size_t)b * S + S - 1) * 512;
  float s = 0.f;
  #pragma unroll
  for (int j = 0; j < 8; j++) { int d = lane * 8 + j; s += hf[base + d] * Wout[d]; }
  #pragma unroll
  for (int o = 32; o >= 1; o >>= 1) s += __shfl_xor(s, o, 64);
  if (lane == 0) out[b] = s + bout[0];
}

extern "C" void kernel_launch(void* const* d_in, const int* in_sizes, int n_in,
                              void* d_out, int out_size, void* d_ws, size_t ws_size,
                              hipStream_t stream) {
  (void)in_sizes; (void)n_in; (void)out_size; (void)ws_size;
  const float* x      = (const float*)d_in[0];
  const float* W_emb  = (const float*)d_in[1];
  const float* b_emb  = (const float*)d_in[2];
  const float* Wqkv_g = (const float*)d_in[3];
  const float* bqkv_g = (const float*)d_in[4];
  const float* Wo_g   = (const float*)d_in[5];
  const float* bo_g   = (const float*)d_in[6];
  const float* Wqkv_l = (const float*)d_in[7];
  const float* bqkv_l = (const float*)d_in[8];
  const float* Wo_l   = (const float*)d_in[9];
  const float* bo_l   = (const float*)d_in[10];
  const float* W1     = (const float*)d_in[11];
  const float* b1f    = (const float*)d_in[12];
  const float* W2     = (const float*)d_in[13];
  const float* b2f    = (const float*)d_in[14];
  const float* g1     = (const float*)d_in[15];
  const float* be1    = (const float*)d_in[16];
  const float* g2     = (const float*)d_in[17];
  const float* be2    = (const float*)d_in[18];
  const float* W_out  = (const float*)d_in[19];
  const float* b_out  = (const float*)d_in[20];
  float* out = (float*)d_out;

  char* ws = (char*)d_ws;
  u16*   w_bf = (u16*)ws;                       // 32 MiB bf16 weights
  float* h_f  = (float*)(ws + 33554432);        // 32 MiB fp32 master
  u16*   h_b  = (u16*)(ws + 67108864);          // 16 MiB bf16 mirror
  u16*   qkv  = (u16*)(ws + 83886080);          // 48 MiB (alive through attention)
  u16*   v_pk = (u16*)(ws + 134217728);         // 16 MiB
  u16*   ctx  = (u16*)(ws + 150994944);         // 16 MiB
  u16*   ff1  = (u16*)(ws + 83886080);          // 64 MiB, aliases dead qkv+v_pk in FFN
  u16*   go   = (u16*)(ws + 167772160);         // 16 MiB bf16 (also ff2)
  u16*   lo   = (u16*)(ws + 184549376);         // 16 MiB bf16 -> total 192 MiB

  u16* wqkvg = w_bf + 0;
  u16* wqkvl = w_bf + 3145728;
  u16* wog   = w_bf + 6291456;
  u16* wol   = w_bf + 7340032;
  u16* w1b   = w_bf + 8388608;
  u16* w2b   = w_bf + 12582912;

  auto cvt = [&](const float* s_, u16* d_, int n) {
    cvt_bf16_kernel<<<(n / 4 + 255) / 256, 256, 0, stream>>>(s_, d_, n / 4);
  };
  cvt(Wqkv_g, wqkvg, 3145728);
  cvt(Wqkv_l, wqkvl, 3145728);
  cvt(Wo_g,   wog,   1048576);
  cvt(Wo_l,   wol,   1048576);
  cvt(W1,     w1b,   4194304);
  cvt(W2,     w2b,   4194304);

  embed_kernel<<<T, 256, 0, stream>>>(x, W_emb, b_emb, h_f, h_b);

  for (int i = 0; i < Ln; i++) {
    // global attention
    gemm_bt_kernel<1><<<dim3(1536 / 128, T / 128), 256, 0, stream>>>(
        h_b, wqkvg + (size_t)i * 786432, bqkv_g + i * 1536, qkv, T, 1536, 512);
    packv_kernel<<<dim3(S / 64, Bsz, NHd), 256, 0, stream>>>(qkv, v_pk);
    flash_kernel<<<dim3(2048), 256, 0, stream>>>(qkv, v_pk, ctx, 2048, 32);
    gemm_bt_kernel<1><<<dim3(512 / 128, T / 128), 256, 0, stream>>>(
        ctx, wog + (size_t)i * 262144, bo_g + i * 512, go, T, 512, 512);
    // local (windowed) attention
    gemm_bt_kernel<1><<<dim3(1536 / 128, T / 128), 256, 0, stream>>>(
        h_b, wqkvl + (size_t)i * 786432, bqkv_l + i * 1536, qkv, T, 1536, 512);
    packv_kernel<<<dim3(S / 64, Bsz, NHd), 256, 0, stream>>>(qkv, v_pk);
    flash_kernel<<<dim3(2048), 256, 0, stream>>>(qkv, v_pk, ctx, 512, 8);
    gemm_bt_kernel<1><<<dim3(512 / 128, T / 128), 256, 0, stream>>>(
        ctx, wol + (size_t)i * 262144, bo_l + i * 512, lo, T, 512, 512);
    // LN1
    ln_kernel<2><<<T / 4, 256, 0, stream>>>(h_f, go, lo, g1 + i * 512, be1 + i * 512, h_f, h_b);
    // FFN
    gemm_bt_kernel<2><<<dim3(FFd / 128, T / 128), 256, 0, stream>>>(
        h_b, w1b + (size_t)i * 1048576, b1f + i * 2048, ff1, T, 2048, 512);
    gemm_bt_kernel<1><<<dim3(512 / 128, T / 128), 256, 0, stream>>>(
        ff1, w2b + (size_t)i * 1048576, b2f + i * 512, go, T, 512, 2048);
    ln_kernel<1><<<T / 4, 256, 0, stream>>>(h_f, go, nullptr, g2 + i * 512, be2 + i * 512, h_f, h_b);
  }

  out_kernel<<<Bsz, 64, 0, stream>>>(h_f, W_out, b_out, out);
}

// Round 7
// 1715.013 us; speedup vs baseline: 2.1658x; 1.0585x over previous
//
#include <hip/hip_runtime.h>
#include <hip/hip_bf16.h>

#define DEV __device__ __forceinline__

typedef __attribute__((ext_vector_type(4))) float f32x4;
typedef __attribute__((ext_vector_type(8))) short s16x8;
typedef unsigned short u16;

constexpr int Bsz = 8;      // batch
constexpr int S   = 2048;   // sequence
constexpr int Dm  = 512;    // model dim
constexpr int NHd = 8;      // heads
constexpr int FFd = 2048;
constexpr int Ln  = 4;
constexpr int T   = S * Bsz; // 16384 tokens; token index t = b*S + s (batch-major)

DEV u16 f2bf(float f) {
  union { float f; unsigned u; } v; v.f = f;
  unsigned r = v.u + 0x7fff + ((v.u >> 16) & 1);
  return (u16)(r >> 16);
}
DEV float bf2f(u16 a) { union { unsigned u; float f; } v; v.u = ((unsigned)a) << 16; return v.f; }
DEV float exp2g(float x) { return __builtin_amdgcn_exp2f(x); }   // v_exp_f32 (base-2 native)

typedef __attribute__((address_space(1))) const unsigned int guint;
typedef __attribute__((address_space(3))) unsigned int luint;
DEV void gload16(const void* g, void* l) {
  __builtin_amdgcn_global_load_lds((guint*)g, (luint*)l, 16, 0, 0);
}

// ---------------- weight fp32 -> bf16 ----------------
__global__ void cvt_bf16_kernel(const float* __restrict__ src, u16* __restrict__ dst, int n4) {
  int i = (blockIdx.x * 256 + threadIdx.x);
  if (i >= n4) return;
  float4 v = *reinterpret_cast<const float4*>(src + i * 4);
  ushort4 o; o.x = f2bf(v.x); o.y = f2bf(v.y); o.z = f2bf(v.z); o.w = f2bf(v.w);
  *reinterpret_cast<ushort4*>(dst + i * 4) = o;
}

// ---------------- Wo fuse: dst[l][n][k], k<512 from Wo_g, else Wo_l (K-concat) ----------------
__global__ void cvt_wo_kernel(const float* __restrict__ g, const float* __restrict__ l,
                              u16* __restrict__ dst) {
  int i = blockIdx.x * 256 + threadIdx.x;          // over 4-elem groups, total L*512*1024/4
  int e = i * 4;
  int li = e >> 19;
  int rem = e & 524287;
  int n = rem >> 10, k = rem & 1023;
  const float* src = (k < 512) ? (g + ((size_t)li * 512 + n) * 512 + k)
                               : (l + ((size_t)li * 512 + n) * 512 + (k - 512));
  float4 v = *reinterpret_cast<const float4*>(src);
  ushort4 o; o.x = f2bf(v.x); o.y = f2bf(v.y); o.z = f2bf(v.z); o.w = f2bf(v.w);
  *reinterpret_cast<ushort4*>(dst + e) = o;
}

// ---------------- embed + positional encoding (token t = b*S + s) ----------------
__global__ void embed_kernel(const float* __restrict__ x, const float* __restrict__ Wemb,
                             const float* __restrict__ bemb, float* __restrict__ hf,
                             u16* __restrict__ hb) {
  int t = blockIdx.x;
  int b = t >> 11, s = t & 2047;
  const float* xr = x + ((size_t)b * S + s) * 14;
  float xv[14];
  #pragma unroll
  for (int i = 0; i < 14; i++) xv[i] = xr[i];
  for (int d = threadIdx.x; d < Dm; d += blockDim.x) {
    const float* wr = Wemb + d * 14;
    float acc = bemb[d];
    #pragma unroll
    for (int i = 0; i < 14; i++) acc += xv[i] * wr[i];
    float ang = (float)s * expf((float)((d >> 1) * 2) * (-9.210340371976184f / 512.0f));
    acc += (d & 1) ? cosf(ang) : sinf(ang);
    hf[(size_t)t * Dm + d] = acc;
    hb[(size_t)t * Dm + d] = f2bf(acc);
  }
}

// ---------------- GEMM: C(M,N) = A(M,K) @ Bt(N,K)^T + bias ----------------
// OMODE: 1 = bf16 out, 2 = bf16 out + relu.
// VPACK (fused qkv GEMM, N=3072): 512-col sections {q_g,k_g,v_g,q_l,k_l,v_l};
//   v-sections scatter transposed into vpk[bh][d][s]; q/k write to qkv[t][2048];
//   bias1 = bqkv_g (cols<1536), bias2 = bqkv_l.
// BSUM: bias = bias1[col] + bias2[col] (fused wo GEMM).
template<int OMODE, int VPACK, int BSUM>
__global__ __launch_bounds__(256, 2)
void gemm_bt_kernel(const u16* __restrict__ A, const u16* __restrict__ Bt,
                    const float* __restrict__ bias1, const float* __restrict__ bias2,
                    void* __restrict__ Cout, u16* __restrict__ vpk,
                    int M, int N, int K) {
  __shared__ __align__(16) u16 As[2][128 * 32];
  __shared__ __align__(16) u16 Bs[2][128 * 32];
  const int tid = threadIdx.x;
  const int lane = tid & 63, w = tid >> 6;
  const int wr = w >> 1, wc = w & 1;
  const int lr = lane & 15, lg = lane >> 4;
  const int m0 = blockIdx.y * 128, n0 = blockIdx.x * 128;

  f32x4 acc[4][4] = {};

  const int c1 = tid, c2 = tid + 256;
  const u16* gA1 = A + (size_t)(m0 + (c1 >> 2)) * K + (c1 & 3) * 8;
  const u16* gA2 = A + (size_t)(m0 + (c2 >> 2)) * K + (c2 & 3) * 8;
  const u16* gB1 = Bt + (size_t)(n0 + (c1 >> 2)) * K + (c1 & 3) * 8;
  const u16* gB2 = Bt + (size_t)(n0 + (c2 >> 2)) * K + (c2 & 3) * 8;

  const int nk = K >> 5;
  auto stage = [&](int t, int c) {
    const int kt = t * 32;
    gload16(gA1 + kt, As[c] + c1 * 8); gload16(gA2 + kt, As[c] + c2 * 8);
    gload16(gB1 + kt, Bs[c] + c1 * 8); gload16(gB2 + kt, Bs[c] + c2 * 8);
  };

  stage(0, 0);
  for (int t = 0; t < nk; ++t) {
    const int c = t & 1;
    if (t + 1 < nk) {
      stage(t + 1, c ^ 1);
      asm volatile("s_waitcnt vmcnt(4)" ::: "memory");
    } else {
      asm volatile("s_waitcnt vmcnt(0)" ::: "memory");
    }
    __builtin_amdgcn_s_barrier();

    s16x8 a[4], bb[4];
    #pragma unroll
    for (int i = 0; i < 4; i++) {
      a[i]  = *reinterpret_cast<const s16x8*>(As[c] + ((wr * 64 + i * 16 + lr) * 32 + lg * 8));
      bb[i] = *reinterpret_cast<const s16x8*>(Bs[c] + ((wc * 64 + i * 16 + lr) * 32 + lg * 8));
    }
    #pragma unroll
    for (int mi = 0; mi < 4; mi++)
      #pragma unroll
      for (int ni = 0; ni < 4; ni++)
        acc[mi][ni] = __builtin_amdgcn_mfma_f32_16x16x32_bf16(a[mi], bb[ni], acc[mi][ni], 0, 0, 0);

    __builtin_amdgcn_s_barrier();
  }

  // epilogue
  const int sec = VPACK ? (n0 >> 9) : 0;            // block-uniform (128 | 512)
  const bool isv = VPACK && (sec == 2 || sec == 5);
  const int ldc = VPACK ? 2048 : N;
  const int csub = (VPACK && sec >= 3) ? 512 : 0;
  u16* vdst = nullptr;
  if (isv) vdst = vpk + (sec == 5 ? 8388608 : 0);

  #pragma unroll
  for (int mi = 0; mi < 4; mi++) {
    int row = m0 + wr * 64 + mi * 16 + lg * 4;
    #pragma unroll
    for (int ni = 0; ni < 4; ni++) {
      int col = n0 + wc * 64 + ni * 16 + lr;
      float bv;
      if (VPACK)      bv = (col < 1536) ? bias1[col] : bias2[col - 1536];
      else if (BSUM)  bv = bias1[col] + bias2[col];
      else            bv = bias1[col];
      if (isv) {
        int vcol = col - (sec == 2 ? 1024 : 2560);
        int hh = vcol >> 6, dd = vcol & 63;
        int bb2 = row >> 11, ss = row & 2047;       // rows = 4 consecutive s within one b
        ushort4 o;
        o.x = f2bf(acc[mi][ni][0] + bv);
        o.y = f2bf(acc[mi][ni][1] + bv);
        o.z = f2bf(acc[mi][ni][2] + bv);
        o.w = f2bf(acc[mi][ni][3] + bv);
        *reinterpret_cast<ushort4*>(vdst + ((size_t)(bb2 * NHd + hh) * 64 + dd) * S + ss) = o;
      } else {
        #pragma unroll
        for (int r = 0; r < 4; r++) {
          float v = acc[mi][ni][r] + bv;
          if (OMODE == 2) v = v > 0.f ? v : 0.f;
          ((u16*)Cout)[(size_t)(row + r) * ldc + (col - csub)] = f2bf(v);
        }
      }
    }
  }
}

// ---------------- flash attention v5b: Q/K from qkv[t][2048], V from vpk ----------------
// 1D grid, bid%8 = h (XCD pin); LDS-staged K/V (dbuf, XOR-swizzled, global_load_lds).
// Swapped mfma(K,Q): lane holds 16 scores of one q-row; exp2 domain; defer-max THR=8.
__global__ __launch_bounds__(256, 3)
void flash_kernel(const u16* __restrict__ qkv, const u16* __restrict__ v_pk,
                  u16* __restrict__ ctx, int S_att, int nqb, int qoff, int koff, int coff) {
  const int tid = threadIdx.x;
  const int lane = tid & 63, w = tid >> 6;
  const int lr = lane & 15, lg = lane >> 4;
  const int bid = blockIdx.x;
  const int h = bid & 7;
  const int r_ = bid >> 3;
  const int qb = r_ % nqb;
  const int cw = r_ / nqb;
  const int b = cw & 7, n = cw >> 3;
  const int s_base = n * S_att;
  const int q0 = qb * 64 + w * 16;

  __shared__ __align__(16) u16 KT[2][4096];   // [key 0..63][dk 0..63], seg-swizzled
  __shared__ __align__(16) u16 VT[2][4096];   // [d 0..63][k 0..63],    seg-swizzled
  __shared__ __align__(16) u16 p_lds_all[4][16][72];
  u16 (*p_lds)[72] = p_lds_all[w];

  const u16* vbase = v_pk + (size_t)(b * NHd + h) * 64 * S + s_base;

  // Q direct load + scale (0.125 * log2e) + repack to bf16
  s16x8 qf[2];
  {
    const u16* qp = qkv + ((size_t)b * S + s_base + q0 + lr) * 2048 + qoff + h * 64 + lg * 8;
    s16x8 r0 = *reinterpret_cast<const s16x8*>(qp);
    s16x8 r1 = *reinterpret_cast<const s16x8*>(qp + 32);
    const float qs = 0.18033688011112042f;
    #pragma unroll
    for (int j = 0; j < 8; j++) {
      qf[0][j] = (short)f2bf(bf2f((u16)r0[j]) * qs);
      qf[1][j] = (short)f2bf(bf2f((u16)r1[j]) * qs);
    }
  }

  s16x8 ones;
  #pragma unroll
  for (int j = 0; j < 8; j++) ones[j] = (short)0x3F80;  // bf16 1.0

  float mrow = -1e30f;                       // running max of q-row lr (log2 units)
  f32x4 lacc = (f32x4){0.f, 0.f, 0.f, 0.f};  // row-sum for rows lg*4+r
  f32x4 oacc[4];
  #pragma unroll
  for (int nt = 0; nt < 4; nt++) oacc[nt] = (f32x4){0.f, 0.f, 0.f, 0.f};

  // staging: thread t covers rows (t>>3) and (t>>3)+32, 16B segment (t&7),
  // global source pre-swizzled seg^=(row&7), LDS dest linear (rule #21).
  const int seg = tid & 7, sr1 = tid >> 3, sr2 = (tid >> 3) + 32;
  const int ssw1 = (seg ^ (sr1 & 7)) * 8, ssw2 = (seg ^ (sr2 & 7)) * 8;

  const u16* kroot = qkv + ((size_t)b * S + s_base) * 2048 + koff + h * 64;

  auto stage = [&](int kb, int c) {
    const u16* kt = kroot + (size_t)kb * 2048;
    gload16(kt + (size_t)sr1 * 2048 + ssw1, &KT[c][tid * 8]);
    gload16(kt + (size_t)sr2 * 2048 + ssw2, &KT[c][2048 + tid * 8]);
    const u16* vt = vbase + kb;
    gload16(vt + (size_t)sr1 * S + ssw1, &VT[c][tid * 8]);
    gload16(vt + (size_t)sr2 * S + ssw2, &VT[c][2048 + tid * 8]);
  };

  stage(0, 0);
  __syncthreads();

  for (int kb = 0; kb < S_att; kb += 64) {
    const int c = (kb >> 6) & 1;
    if (kb + 64 < S_att) stage(kb + 64, c ^ 1);   // prefetch: drains at end-of-iter barrier

    // K^T Q: rows = keys, cols = q
    f32x4 sg[4];
    __builtin_amdgcn_s_setprio(1);
    #pragma unroll
    for (int g = 0; g < 4; g++) {
      const int key = g * 16 + lr, kw = key & 7;
      const u16* kp = &KT[c][key * 64];
      s16x8 k0 = *reinterpret_cast<const s16x8*>(kp + ((lg ^ kw) * 8));
      s16x8 k1 = *reinterpret_cast<const s16x8*>(kp + (((4 + lg) ^ kw) * 8));
      f32x4 sc = (f32x4){0.f, 0.f, 0.f, 0.f};
      sc = __builtin_amdgcn_mfma_f32_16x16x32_bf16(k0, qf[0], sc, 0, 0, 0);
      sc = __builtin_amdgcn_mfma_f32_16x16x32_bf16(k1, qf[1], sc, 0, 0, 0);
      sg[g] = sc;   // sg[g][r] = score(k = kb + g*16 + lg*4 + r, q = lr)
    }
    __builtin_amdgcn_s_setprio(0);

    // tile max of q-row lr: per-lane tree, then reduce across lg (xor 16,32)
    float t0 = fmaxf(fmaxf(sg[0][0], sg[0][1]), fmaxf(sg[0][2], sg[0][3]));
    float t1 = fmaxf(fmaxf(sg[1][0], sg[1][1]), fmaxf(sg[1][2], sg[1][3]));
    float t2 = fmaxf(fmaxf(sg[2][0], sg[2][1]), fmaxf(sg[2][2], sg[2][3]));
    float t3 = fmaxf(fmaxf(sg[3][0], sg[3][1]), fmaxf(sg[3][2], sg[3][3]));
    float tmax = fmaxf(fmaxf(t0, t1), fmaxf(t2, t3));
    tmax = fmaxf(tmax, __shfl_xor(tmax, 16, 64));
    tmax = fmaxf(tmax, __shfl_xor(tmax, 32, 64));

    // defer-max (T13): only rescale when some row grew by > 8 (log2 units; P <= 2^8)
    if (__any((int)(tmax > mrow + 8.f))) {
      float mnew = fmaxf(mrow, tmax);
      float cf = exp2g(mrow - mnew);   // correction for q-row lr
      mrow = mnew;
      #pragma unroll
      for (int r = 0; r < 4; r++) {
        float co = __shfl(cf, lg * 4 + r, 16);   // correction for q-row lg*4+r
        lacc[r] *= co;
        #pragma unroll
        for (int nt = 0; nt < 4; nt++) oacc[nt][r] *= co;
      }
    }

    // P -> LDS: exp2, pack pairs with v_cvt_pk_bf16_f32, b64 write (4 consecutive k)
    asm volatile("s_waitcnt lgkmcnt(0)" ::: "memory");  // WAR vs previous iter's reads
    #pragma unroll
    for (int g = 0; g < 4; g++) {
      float e0 = exp2g(sg[g][0] - mrow);
      float e1 = exp2g(sg[g][1] - mrow);
      float e2 = exp2g(sg[g][2] - mrow);
      float e3 = exp2g(sg[g][3] - mrow);
      unsigned p01, p23;
      asm("v_cvt_pk_bf16_f32 %0, %1, %2" : "=v"(p01) : "v"(e0), "v"(e1));
      asm("v_cvt_pk_bf16_f32 %0, %1, %2" : "=v"(p23) : "v"(e2), "v"(e3));
      uint2 pk; pk.x = p01; pk.y = p23;
      *reinterpret_cast<uint2*>(&p_lds[lr][g * 16 + lg * 4]) = pk;
    }
    asm volatile("s_waitcnt lgkmcnt(0)" ::: "memory");  // RAW: writes visible within wave

    __builtin_amdgcn_s_setprio(1);
    #pragma unroll
    for (int kc = 0; kc < 2; kc++) {
      s16x8 pa = *reinterpret_cast<const s16x8*>(&p_lds[lr][kc * 32 + lg * 8]);
      lacc = __builtin_amdgcn_mfma_f32_16x16x32_bf16(pa, ones, lacc, 0, 0, 0);  // row-sum
      #pragma unroll
      for (int nt = 0; nt < 4; nt++) {
        const int d = nt * 16 + lr;
        s16x8 vfr = *reinterpret_cast<const s16x8*>(
            &VT[c][d * 64 + (((kc * 4 + lg) ^ (d & 7)) * 8)]);
        oacc[nt] = __builtin_amdgcn_mfma_f32_16x16x32_bf16(pa, vfr, oacc[nt], 0, 0, 0);
      }
    }
    __builtin_amdgcn_s_setprio(0);

    __syncthreads();  // drains stage vmcnt + all LDS reads; flips buffers safely
  }

  #pragma unroll
  for (int nt = 0; nt < 4; nt++)
    #pragma unroll
    for (int r = 0; r < 4; r++) {
      float v = oacc[nt][r] / lacc[r];
      size_t tq = (size_t)b * S + s_base + q0 + lg * 4 + r;
      ctx[tq * 1024 + coff + h * 64 + nt * 16 + lr] = f2bf(v);
    }
}

// ---------------- residual add (bf16 branch) + LayerNorm ----------------
template<int NADD>
__global__ void ln_kernel(const float* __restrict__ hin, const u16* __restrict__ a1,
                          const u16* __restrict__ a2, const float* __restrict__ gamma,
                          const float* __restrict__ beta, float* __restrict__ hf,
                          u16* __restrict__ hb) {
  int row = blockIdx.x * 4 + (threadIdx.x >> 6);
  int lane = threadIdx.x & 63;
  size_t base = (size_t)row * 512 + lane * 8;
  float4 h0 = *reinterpret_cast<const float4*>(hin + base);
  float4 h1 = *reinterpret_cast<const float4*>(hin + base + 4);
  s16x8 x1 = *reinterpret_cast<const s16x8*>(a1 + base);
  s16x8 x2 = {};
  if (NADD == 2) x2 = *reinterpret_cast<const s16x8*>(a2 + base);
  float v[8];
  float hv[8] = {h0.x, h0.y, h0.z, h0.w, h1.x, h1.y, h1.z, h1.w};
  float sum = 0.f;
  #pragma unroll
  for (int j = 0; j < 8; j++) {
    float t = hv[j] + bf2f((u16)x1[j]);
    if (NADD == 2) t += bf2f((u16)x2[j]);
    v[j] = t; sum += t;
  }
  #pragma unroll
  for (int o = 32; o >= 1; o >>= 1) sum += __shfl_xor(sum, o, 64);
  float mean = sum * (1.0f / 512.0f);
  float sq = 0.f;
  #pragma unroll
  for (int j = 0; j < 8; j++) { float d = v[j] - mean; sq += d * d; }
  #pragma unroll
  for (int o = 32; o >= 1; o >>= 1) sq += __shfl_xor(sq, o, 64);
  float rstd = rsqrtf(sq * (1.0f / 512.0f) + 1e-5f);
  #pragma unroll
  for (int j = 0; j < 8; j++) {
    int d = lane * 8 + j;
    float o = (v[j] - mean) * rstd * gamma[d] + beta[d];
    hf[base + j] = o;
    hb[base + j] = f2bf(o);
  }
}

// ---------------- final projection (token (s=S-1, b) = b*S + S-1) ----------------
__global__ void out_kernel(const float* __restrict__ hf, const float* __restrict__ Wout,
                           const float* __restrict__ bout, float* __restrict__ out) {
  int b = blockIdx.x; int lane = threadIdx.x;
  size_t base = ((size_t)b * S + S - 1) * 512;
  float s = 0.f;
  #pragma unroll
  for (int j = 0; j < 8; j++) { int d = lane * 8 + j; s += hf[base + d] * Wout[d]; }
  #pragma unroll
  for (int o = 32; o >= 1; o >>= 1) s += __shfl_xor(s, o, 64);
  if (lane == 0) out[b] = s + bout[0];
}

extern "C" void kernel_launch(void* const* d_in, const int* in_sizes, int n_in,
                              void* d_out, int out_size, void* d_ws, size_t ws_size,
                              hipStream_t stream) {
  (void)in_sizes; (void)n_in; (void)out_size; (void)ws_size;
  const float* x      = (const float*)d_in[0];
  const float* W_emb  = (const float*)d_in[1];
  const float* b_emb  = (const float*)d_in[2];
  const float* Wqkv_g = (const float*)d_in[3];
  const float* bqkv_g = (const float*)d_in[4];
  const float* Wo_g   = (const float*)d_in[5];
  const float* bo_g   = (const float*)d_in[6];
  const float* Wqkv_l = (const float*)d_in[7];
  const float* bqkv_l = (const float*)d_in[8];
  const float* Wo_l   = (const float*)d_in[9];
  const float* bo_l   = (const float*)d_in[10];
  const float* W1     = (const float*)d_in[11];
  const float* b1f    = (const float*)d_in[12];
  const float* W2     = (const float*)d_in[13];
  const float* b2f    = (const float*)d_in[14];
  const float* g1     = (const float*)d_in[15];
  const float* be1    = (const float*)d_in[16];
  const float* g2     = (const float*)d_in[17];
  const float* be2    = (const float*)d_in[18];
  const float* W_out  = (const float*)d_in[19];
  const float* b_out  = (const float*)d_in[20];
  float* out = (float*)d_out;

  char* ws = (char*)d_ws;
  u16*   w_bf = (u16*)ws;                       // 32 MiB bf16 weights
  float* h_f  = (float*)(ws + 33554432);        // 32 MiB fp32 master
  u16*   h_b  = (u16*)(ws + 67108864);          // 16 MiB bf16 mirror
  u16*   qkv  = (u16*)(ws + 83886080);          // 64 MiB: [t][2048] = {q_g,k_g,q_l,k_l}
  u16*   ff1  = (u16*)(ws + 83886080);          // aliases qkv (dead by FFN)
  u16*   vpk  = (u16*)(ws + 150994944);         // 32 MiB: v_pk_g | v_pk_l (+8388608 elems)
  u16*   ctx  = (u16*)(ws + 184549376);         // 32 MiB: [t][1024] = ctx_g | ctx_l
  u16*   go   = (u16*)(ws + 218103808);         // 16 MiB bf16 (wo out, also ff2 out) -> 224 MiB

  // fused weight layouts
  u16* wqkvF = w_bf;                 // per layer [3072][512]: rows 0-1535 g, 1536-3071 l
  u16* woF   = w_bf + 6291456;       // per layer [512][1024]: k<512 g, k>=512 l
  u16* w1b   = w_bf + 8388608;
  u16* w2b   = w_bf + 12582912;

  auto cvt = [&](const float* s_, u16* d_, int n) {
    cvt_bf16_kernel<<<(n / 4 + 255) / 256, 256, 0, stream>>>(s_, d_, n / 4);
  };
  for (int i = 0; i < Ln; i++) {
    cvt(Wqkv_g + (size_t)i * 786432, wqkvF + (size_t)i * 1572864, 786432);
    cvt(Wqkv_l + (size_t)i * 786432, wqkvF + (size_t)i * 1572864 + 786432, 786432);
  }
  cvt_wo_kernel<<<2048, 256, 0, stream>>>(Wo_g, Wo_l, woF);
  cvt(W1, w1b, 4194304);
  cvt(W2, w2b, 4194304);

  embed_kernel<<<T, 256, 0, stream>>>(x, W_emb, b_emb, h_f, h_b);

  for (int i = 0; i < Ln; i++) {
    // fused qkv (global+local) with V-transpose epilogue
    gemm_bt_kernel<1, 1, 0><<<dim3(3072 / 128, T / 128), 256, 0, stream>>>(
        h_b, wqkvF + (size_t)i * 1572864, bqkv_g + i * 1536, bqkv_l + i * 1536,
        qkv, vpk, T, 3072, 512);
    // global attention -> ctx[:, 0:512]
    flash_kernel<<<dim3(2048), 256, 0, stream>>>(qkv, vpk, ctx, 2048, 32, 0, 512, 0);
    // local attention -> ctx[:, 512:1024]
    flash_kernel<<<dim3(2048), 256, 0, stream>>>(qkv, vpk + 8388608, ctx, 512, 8, 1024, 1536, 512);
    // fused output projection: [ctx_g|ctx_l] @ [Wo_g;Wo_l], bias = bo_g + bo_l
    gemm_bt_kernel<1, 0, 1><<<dim3(512 / 128, T / 128), 256, 0, stream>>>(
        ctx, woF + (size_t)i * 524288, bo_g + i * 512, bo_l + i * 512,
        go, nullptr, T, 512, 1024);
    // LN1
    ln_kernel<1><<<T / 4, 256, 0, stream>>>(h_f, go, nullptr, g1 + i * 512, be1 + i * 512, h_f, h_b);
    // FFN
    gemm_bt_kernel<2, 0, 0><<<dim3(FFd / 128, T / 128), 256, 0, stream>>>(
        h_b, w1b + (size_t)i * 1048576, b1f + i * 2048, nullptr, ff1, nullptr, T, 2048, 512);
    gemm_bt_kernel<1, 0, 0><<<dim3(512 / 128, T / 128), 256, 0, stream>>>(
        ff1, w2b + (size_t)i * 1048576, b2f + i * 512, nullptr, go, nullptr, T, 512, 2048);
    ln_kernel<1><<<T / 4, 256, 0, stream>>>(h_f, go, nullptr, g2 + i * 512, be2 + i * 512, h_f, h_b);
  }

  out_kernel<<<Bsz, 64, 0, stream>>>(h_f, W_out, b_out, out);
}

// Round 8
// 1658.854 us; speedup vs baseline: 2.2391x; 1.0339x over previous
//
#include <hip/hip_runtime.h>
#include <hip/hip_bf16.h>

#define DEV __device__ __forceinline__

typedef __attribute__((ext_vector_type(4))) float f32x4;
typedef __attribute__((ext_vector_type(8))) short s16x8;
typedef unsigned short u16;

constexpr int Bsz = 8;      // batch
constexpr int S   = 2048;   // sequence
constexpr int Dm  = 512;    // model dim
constexpr int NHd = 8;      // heads
constexpr int FFd = 2048;
constexpr int Ln  = 4;
constexpr int T   = S * Bsz; // 16384 tokens; token index t = b*S + s (batch-major)

DEV u16 f2bf(float f) {
  union { float f; unsigned u; } v; v.f = f;
  unsigned r = v.u + 0x7fff + ((v.u >> 16) & 1);
  return (u16)(r >> 16);
}
DEV float bf2f(u16 a) { union { unsigned u; float f; } v; v.u = ((unsigned)a) << 16; return v.f; }
DEV float exp2g(float x) { return __builtin_amdgcn_exp2f(x); }   // v_exp_f32 (base-2 native)

typedef __attribute__((address_space(1))) const unsigned int guint;
typedef __attribute__((address_space(3))) unsigned int luint;
DEV void gload16(const void* g, void* l) {
  __builtin_amdgcn_global_load_lds((guint*)g, (luint*)l, 16, 0, 0);
}

// ---------------- weight fp32 -> bf16 ----------------
__global__ void cvt_bf16_kernel(const float* __restrict__ src, u16* __restrict__ dst, int n4) {
  int i = (blockIdx.x * 256 + threadIdx.x);
  if (i >= n4) return;
  float4 v = *reinterpret_cast<const float4*>(src + i * 4);
  ushort4 o; o.x = f2bf(v.x); o.y = f2bf(v.y); o.z = f2bf(v.z); o.w = f2bf(v.w);
  *reinterpret_cast<ushort4*>(dst + i * 4) = o;
}

// ---------------- Wo fuse: dst[l][n][k], k<512 from Wo_g, else Wo_l (K-concat) ----------------
__global__ void cvt_wo_kernel(const float* __restrict__ g, const float* __restrict__ l,
                              u16* __restrict__ dst) {
  int i = blockIdx.x * 256 + threadIdx.x;          // over 4-elem groups, total L*512*1024/4
  int e = i * 4;
  int li = e >> 19;
  int rem = e & 524287;
  int n = rem >> 10, k = rem & 1023;
  const float* src = (k < 512) ? (g + ((size_t)li * 512 + n) * 512 + k)
                               : (l + ((size_t)li * 512 + n) * 512 + (k - 512));
  float4 v = *reinterpret_cast<const float4*>(src);
  ushort4 o; o.x = f2bf(v.x); o.y = f2bf(v.y); o.z = f2bf(v.z); o.w = f2bf(v.w);
  *reinterpret_cast<ushort4*>(dst + e) = o;
}

// ---------------- embed + positional encoding (token t = b*S + s) ----------------
__global__ void embed_kernel(const float* __restrict__ x, const float* __restrict__ Wemb,
                             const float* __restrict__ bemb, float* __restrict__ hf,
                             u16* __restrict__ hb) {
  int t = blockIdx.x;
  int b = t >> 11, s = t & 2047;
  const float* xr = x + ((size_t)b * S + s) * 14;
  float xv[14];
  #pragma unroll
  for (int i = 0; i < 14; i++) xv[i] = xr[i];
  for (int d = threadIdx.x; d < Dm; d += blockDim.x) {
    const float* wr = Wemb + d * 14;
    float acc = bemb[d];
    #pragma unroll
    for (int i = 0; i < 14; i++) acc += xv[i] * wr[i];
    float ang = (float)s * expf((float)((d >> 1) * 2) * (-9.210340371976184f / 512.0f));
    acc += (d & 1) ? cosf(ang) : sinf(ang);
    hf[(size_t)t * Dm + d] = acc;
    hb[(size_t)t * Dm + d] = f2bf(acc);
  }
}

// ---------------- GEMM: C(M,N) = A(M,K) @ Bt(N,K)^T + bias ----------------
// OMODE: 1 = bf16 out, 2 = bf16 out + relu.
// VPACK (fused qkv GEMM, N=3072): 512-col sections {q_g,k_g,v_g,q_l,k_l,v_l};
//   v-sections scatter transposed into vpk[bh][d][s]; q/k write to qkv[t][2048];
//   bias1 = bqkv_g (cols<1536), bias2 = bqkv_l.
// BSUM: bias = bias1[col] + bias2[col] (fused wo GEMM).
template<int OMODE, int VPACK, int BSUM>
__global__ __launch_bounds__(256, 2)
void gemm_bt_kernel(const u16* __restrict__ A, const u16* __restrict__ Bt,
                    const float* __restrict__ bias1, const float* __restrict__ bias2,
                    void* __restrict__ Cout, u16* __restrict__ vpk,
                    int M, int N, int K) {
  __shared__ __align__(16) u16 As[2][128 * 32];
  __shared__ __align__(16) u16 Bs[2][128 * 32];
  const int tid = threadIdx.x;
  const int lane = tid & 63, w = tid >> 6;
  const int wr = w >> 1, wc = w & 1;
  const int lr = lane & 15, lg = lane >> 4;
  const int m0 = blockIdx.y * 128, n0 = blockIdx.x * 128;

  f32x4 acc[4][4] = {};

  const int c1 = tid, c2 = tid + 256;
  const u16* gA1 = A + (size_t)(m0 + (c1 >> 2)) * K + (c1 & 3) * 8;
  const u16* gA2 = A + (size_t)(m0 + (c2 >> 2)) * K + (c2 & 3) * 8;
  const u16* gB1 = Bt + (size_t)(n0 + (c1 >> 2)) * K + (c1 & 3) * 8;
  const u16* gB2 = Bt + (size_t)(n0 + (c2 >> 2)) * K + (c2 & 3) * 8;

  const int nk = K >> 5;
  auto stage = [&](int t, int c) {
    const int kt = t * 32;
    gload16(gA1 + kt, As[c] + c1 * 8); gload16(gA2 + kt, As[c] + c2 * 8);
    gload16(gB1 + kt, Bs[c] + c1 * 8); gload16(gB2 + kt, Bs[c] + c2 * 8);
  };

  stage(0, 0);
  for (int t = 0; t < nk; ++t) {
    const int c = t & 1;
    if (t + 1 < nk) {
      stage(t + 1, c ^ 1);
      asm volatile("s_waitcnt vmcnt(4)" ::: "memory");
    } else {
      asm volatile("s_waitcnt vmcnt(0)" ::: "memory");
    }
    __builtin_amdgcn_s_barrier();

    s16x8 a[4], bb[4];
    #pragma unroll
    for (int i = 0; i < 4; i++) {
      a[i]  = *reinterpret_cast<const s16x8*>(As[c] + ((wr * 64 + i * 16 + lr) * 32 + lg * 8));
      bb[i] = *reinterpret_cast<const s16x8*>(Bs[c] + ((wc * 64 + i * 16 + lr) * 32 + lg * 8));
    }
    #pragma unroll
    for (int mi = 0; mi < 4; mi++)
      #pragma unroll
      for (int ni = 0; ni < 4; ni++)
        acc[mi][ni] = __builtin_amdgcn_mfma_f32_16x16x32_bf16(a[mi], bb[ni], acc[mi][ni], 0, 0, 0);

    __builtin_amdgcn_s_barrier();
  }

  // epilogue
  const int sec = VPACK ? (n0 >> 9) : 0;            // block-uniform (128 | 512)
  const bool isv = VPACK && (sec == 2 || sec == 5);
  const int ldc = VPACK ? 2048 : N;
  const int csub = (VPACK && sec >= 3) ? 512 : 0;
  u16* vdst = nullptr;
  if (isv) vdst = vpk + (sec == 5 ? 8388608 : 0);

  #pragma unroll
  for (int mi = 0; mi < 4; mi++) {
    int row = m0 + wr * 64 + mi * 16 + lg * 4;
    #pragma unroll
    for (int ni = 0; ni < 4; ni++) {
      int col = n0 + wc * 64 + ni * 16 + lr;
      float bv;
      if (VPACK)      bv = (col < 1536) ? bias1[col] : bias2[col - 1536];
      else if (BSUM)  bv = bias1[col] + bias2[col];
      else            bv = bias1[col];
      if (isv) {
        int vcol = col - (sec == 2 ? 1024 : 2560);
        int hh = vcol >> 6, dd = vcol & 63;
        int bb2 = row >> 11, ss = row & 2047;       // rows = 4 consecutive s within one b
        ushort4 o;
        o.x = f2bf(acc[mi][ni][0] + bv);
        o.y = f2bf(acc[mi][ni][1] + bv);
        o.z = f2bf(acc[mi][ni][2] + bv);
        o.w = f2bf(acc[mi][ni][3] + bv);
        *reinterpret_cast<ushort4*>(vdst + ((size_t)(bb2 * NHd + hh) * 64 + dd) * S + ss) = o;
      } else {
        #pragma unroll
        for (int r = 0; r < 4; r++) {
          float v = acc[mi][ni][r] + bv;
          if (OMODE == 2) v = v > 0.f ? v : 0.f;
          ((u16*)Cout)[(size_t)(row + r) * ldc + (col - csub)] = f2bf(v);
        }
      }
    }
  }
}

// ---------------- flash attention v6: 2 q-tiles per wave (32 q-rows), shared K/V ----------------
// Block = 128 q-rows (4 waves x 2 tiles of 16). K/V staged once per 64-k tile, used by
// both q-tiles -> staging/barrier cost per unit work halves; tile-B softmax VALU overlaps
// tile-A PV MFMA. Swapped mfma(K,Q); exp2 domain; defer-max THR=8; XOR-swizzled LDS.
__global__ __launch_bounds__(256, 3)
void flash_kernel(const u16* __restrict__ qkv, const u16* __restrict__ v_pk,
                  u16* __restrict__ ctx, int S_att, int nqb, int qoff, int koff, int coff) {
  const int tid = threadIdx.x;
  const int lane = tid & 63, w = tid >> 6;
  const int lr = lane & 15, lg = lane >> 4;
  const int bid = blockIdx.x;
  const int h = bid & 7;
  const int r_ = bid >> 3;
  const int qb = r_ % nqb;
  const int cw = r_ / nqb;
  const int b = cw & 7, n = cw >> 3;
  const int s_base = n * S_att;
  const int q0A = qb * 128 + w * 16;      // tile A rows
  const int q0B = q0A + 64;               // tile B rows

  __shared__ __align__(16) u16 KT[2][4096];   // [key 0..63][dk 0..63], seg-swizzled
  __shared__ __align__(16) u16 VT[2][4096];   // [d 0..63][k 0..63],    seg-swizzled
  __shared__ __align__(16) u16 p_lds_all[4][16][72];
  u16 (*p_lds)[72] = p_lds_all[w];

  const u16* vbase = v_pk + (size_t)(b * NHd + h) * 64 * S + s_base;

  // Q direct load + scale (0.125 * log2e) + repack to bf16, both tiles
  s16x8 qfA[2], qfB[2];
  {
    const float qs = 0.18033688011112042f;
    const u16* qpA = qkv + ((size_t)b * S + s_base + q0A + lr) * 2048 + qoff + h * 64 + lg * 8;
    const u16* qpB = qkv + ((size_t)b * S + s_base + q0B + lr) * 2048 + qoff + h * 64 + lg * 8;
    s16x8 a0 = *reinterpret_cast<const s16x8*>(qpA);
    s16x8 a1 = *reinterpret_cast<const s16x8*>(qpA + 32);
    s16x8 b0 = *reinterpret_cast<const s16x8*>(qpB);
    s16x8 b1 = *reinterpret_cast<const s16x8*>(qpB + 32);
    #pragma unroll
    for (int j = 0; j < 8; j++) {
      qfA[0][j] = (short)f2bf(bf2f((u16)a0[j]) * qs);
      qfA[1][j] = (short)f2bf(bf2f((u16)a1[j]) * qs);
      qfB[0][j] = (short)f2bf(bf2f((u16)b0[j]) * qs);
      qfB[1][j] = (short)f2bf(bf2f((u16)b1[j]) * qs);
    }
  }

  s16x8 ones;
  #pragma unroll
  for (int j = 0; j < 8; j++) ones[j] = (short)0x3F80;  // bf16 1.0

  float mA = -1e30f, mB = -1e30f;
  f32x4 laccA = (f32x4){0.f, 0.f, 0.f, 0.f}, laccB = (f32x4){0.f, 0.f, 0.f, 0.f};
  f32x4 oaccA[4], oaccB[4];
  #pragma unroll
  for (int nt = 0; nt < 4; nt++) {
    oaccA[nt] = (f32x4){0.f, 0.f, 0.f, 0.f};
    oaccB[nt] = (f32x4){0.f, 0.f, 0.f, 0.f};
  }

  // staging: thread t covers rows (t>>3) and (t>>3)+32, 16B segment (t&7),
  // global source pre-swizzled seg^=(row&7), LDS dest linear (rule #21).
  const int seg = tid & 7, sr1 = tid >> 3, sr2 = (tid >> 3) + 32;
  const int ssw1 = (seg ^ (sr1 & 7)) * 8, ssw2 = (seg ^ (sr2 & 7)) * 8;

  const u16* kroot = qkv + ((size_t)b * S + s_base) * 2048 + koff + h * 64;

  auto stage = [&](int kb, int c) {
    const u16* kt = kroot + (size_t)kb * 2048;
    gload16(kt + (size_t)sr1 * 2048 + ssw1, &KT[c][tid * 8]);
    gload16(kt + (size_t)sr2 * 2048 + ssw2, &KT[c][2048 + tid * 8]);
    const u16* vt = vbase + kb;
    gload16(vt + (size_t)sr1 * S + ssw1, &VT[c][tid * 8]);
    gload16(vt + (size_t)sr2 * S + ssw2, &VT[c][2048 + tid * 8]);
  };

  stage(0, 0);
  __syncthreads();

  for (int kb = 0; kb < S_att; kb += 64) {
    const int c = (kb >> 6) & 1;
    if (kb + 64 < S_att) stage(kb + 64, c ^ 1);   // prefetch: drains at end-of-iter barrier

    // K^T Q for both tiles (16 MFMA issued back-to-back)
    f32x4 sgA[4], sgB[4];
    __builtin_amdgcn_s_setprio(1);
    #pragma unroll
    for (int g = 0; g < 4; g++) {
      const int key = g * 16 + lr, kw = key & 7;
      const u16* kp = &KT[c][key * 64];
      s16x8 k0 = *reinterpret_cast<const s16x8*>(kp + ((lg ^ kw) * 8));
      s16x8 k1 = *reinterpret_cast<const s16x8*>(kp + (((4 + lg) ^ kw) * 8));
      f32x4 sa = (f32x4){0.f, 0.f, 0.f, 0.f};
      sa = __builtin_amdgcn_mfma_f32_16x16x32_bf16(k0, qfA[0], sa, 0, 0, 0);
      sa = __builtin_amdgcn_mfma_f32_16x16x32_bf16(k1, qfA[1], sa, 0, 0, 0);
      sgA[g] = sa;
      f32x4 sb = (f32x4){0.f, 0.f, 0.f, 0.f};
      sb = __builtin_amdgcn_mfma_f32_16x16x32_bf16(k0, qfB[0], sb, 0, 0, 0);
      sb = __builtin_amdgcn_mfma_f32_16x16x32_bf16(k1, qfB[1], sb, 0, 0, 0);
      sgB[g] = sb;
    }
    __builtin_amdgcn_s_setprio(0);

    // softmax maxes for both tiles
    float tmA, tmB;
    {
      float t0 = fmaxf(fmaxf(sgA[0][0], sgA[0][1]), fmaxf(sgA[0][2], sgA[0][3]));
      float t1 = fmaxf(fmaxf(sgA[1][0], sgA[1][1]), fmaxf(sgA[1][2], sgA[1][3]));
      float t2 = fmaxf(fmaxf(sgA[2][0], sgA[2][1]), fmaxf(sgA[2][2], sgA[2][3]));
      float t3 = fmaxf(fmaxf(sgA[3][0], sgA[3][1]), fmaxf(sgA[3][2], sgA[3][3]));
      tmA = fmaxf(fmaxf(t0, t1), fmaxf(t2, t3));
      tmA = fmaxf(tmA, __shfl_xor(tmA, 16, 64));
      tmA = fmaxf(tmA, __shfl_xor(tmA, 32, 64));
      float u0 = fmaxf(fmaxf(sgB[0][0], sgB[0][1]), fmaxf(sgB[0][2], sgB[0][3]));
      float u1 = fmaxf(fmaxf(sgB[1][0], sgB[1][1]), fmaxf(sgB[1][2], sgB[1][3]));
      float u2 = fmaxf(fmaxf(sgB[2][0], sgB[2][1]), fmaxf(sgB[2][2], sgB[2][3]));
      float u3 = fmaxf(fmaxf(sgB[3][0], sgB[3][1]), fmaxf(sgB[3][2], sgB[3][3]));
      tmB = fmaxf(fmaxf(u0, u1), fmaxf(u2, u3));
      tmB = fmaxf(tmB, __shfl_xor(tmB, 16, 64));
      tmB = fmaxf(tmB, __shfl_xor(tmB, 32, 64));
    }
    if (__any((int)(tmA > mA + 8.f))) {          // defer-max tile A
      float mnew = fmaxf(mA, tmA);
      float cf = exp2g(mA - mnew);
      mA = mnew;
      #pragma unroll
      for (int r = 0; r < 4; r++) {
        float co = __shfl(cf, lg * 4 + r, 16);
        laccA[r] *= co;
        #pragma unroll
        for (int nt = 0; nt < 4; nt++) oaccA[nt][r] *= co;
      }
    }
    if (__any((int)(tmB > mB + 8.f))) {          // defer-max tile B
      float mnew = fmaxf(mB, tmB);
      float cf = exp2g(mB - mnew);
      mB = mnew;
      #pragma unroll
      for (int r = 0; r < 4; r++) {
        float co = __shfl(cf, lg * 4 + r, 16);
        laccB[r] *= co;
        #pragma unroll
        for (int nt = 0; nt < 4; nt++) oaccB[nt][r] *= co;
      }
    }

    // ---- tile A: P -> LDS, PV ----
    asm volatile("s_waitcnt lgkmcnt(0)" ::: "memory");  // WAR vs previous iter's reads
    #pragma unroll
    for (int g = 0; g < 4; g++) {
      float e0 = exp2g(sgA[g][0] - mA);
      float e1 = exp2g(sgA[g][1] - mA);
      float e2 = exp2g(sgA[g][2] - mA);
      float e3 = exp2g(sgA[g][3] - mA);
      unsigned p01, p23;
      asm("v_cvt_pk_bf16_f32 %0, %1, %2" : "=v"(p01) : "v"(e0), "v"(e1));
      asm("v_cvt_pk_bf16_f32 %0, %1, %2" : "=v"(p23) : "v"(e2), "v"(e3));
      uint2 pk; pk.x = p01; pk.y = p23;
      *reinterpret_cast<uint2*>(&p_lds[lr][g * 16 + lg * 4]) = pk;
    }
    asm volatile("s_waitcnt lgkmcnt(0)" ::: "memory");  // RAW: writes visible within wave

    __builtin_amdgcn_s_setprio(1);
    #pragma unroll
    for (int kc = 0; kc < 2; kc++) {
      s16x8 pa = *reinterpret_cast<const s16x8*>(&p_lds[lr][kc * 32 + lg * 8]);
      laccA = __builtin_amdgcn_mfma_f32_16x16x32_bf16(pa, ones, laccA, 0, 0, 0);
      #pragma unroll
      for (int nt = 0; nt < 4; nt++) {
        const int d = nt * 16 + lr;
        s16x8 vfr = *reinterpret_cast<const s16x8*>(
            &VT[c][d * 64 + (((kc * 4 + lg) ^ (d & 7)) * 8)]);
        oaccA[nt] = __builtin_amdgcn_mfma_f32_16x16x32_bf16(pa, vfr, oaccA[nt], 0, 0, 0);
      }
    }
    __builtin_amdgcn_s_setprio(0);

    // ---- tile B: P -> LDS, PV ----
    asm volatile("s_waitcnt lgkmcnt(0)" ::: "memory");  // WAR vs tile A's pa reads
    #pragma unroll
    for (int g = 0; g < 4; g++) {
      float e0 = exp2g(sgB[g][0] - mB);
      float e1 = exp2g(sgB[g][1] - mB);
      float e2 = exp2g(sgB[g][2] - mB);
      float e3 = exp2g(sgB[g][3] - mB);
      unsigned p01, p23;
      asm("v_cvt_pk_bf16_f32 %0, %1, %2" : "=v"(p01) : "v"(e0), "v"(e1));
      asm("v_cvt_pk_bf16_f32 %0, %1, %2" : "=v"(p23) : "v"(e2), "v"(e3));
      uint2 pk; pk.x = p01; pk.y = p23;
      *reinterpret_cast<uint2*>(&p_lds[lr][g * 16 + lg * 4]) = pk;
    }
    asm volatile("s_waitcnt lgkmcnt(0)" ::: "memory");

    __builtin_amdgcn_s_setprio(1);
    #pragma unroll
    for (int kc = 0; kc < 2; kc++) {
      s16x8 pa = *reinterpret_cast<const s16x8*>(&p_lds[lr][kc * 32 + lg * 8]);
      laccB = __builtin_amdgcn_mfma_f32_16x16x32_bf16(pa, ones, laccB, 0, 0, 0);
      #pragma unroll
      for (int nt = 0; nt < 4; nt++) {
        const int d = nt * 16 + lr;
        s16x8 vfr = *reinterpret_cast<const s16x8*>(
            &VT[c][d * 64 + (((kc * 4 + lg) ^ (d & 7)) * 8)]);
        oaccB[nt] = __builtin_amdgcn_mfma_f32_16x16x32_bf16(pa, vfr, oaccB[nt], 0, 0, 0);
      }
    }
    __builtin_amdgcn_s_setprio(0);

    __syncthreads();  // drains stage vmcnt + all LDS reads; flips buffers safely
  }

  #pragma unroll
  for (int nt = 0; nt < 4; nt++)
    #pragma unroll
    for (int r = 0; r < 4; r++) {
      float vA = oaccA[nt][r] / laccA[r];
      size_t tqA = (size_t)b * S + s_base + q0A + lg * 4 + r;
      ctx[tqA * 1024 + coff + h * 64 + nt * 16 + lr] = f2bf(vA);
      float vB = oaccB[nt][r] / laccB[r];
      size_t tqB = (size_t)b * S + s_base + q0B + lg * 4 + r;
      ctx[tqB * 1024 + coff + h * 64 + nt * 16 + lr] = f2bf(vB);
    }
}

// ---------------- residual add (bf16 branch) + LayerNorm ----------------
template<int NADD>
__global__ void ln_kernel(const float* __restrict__ hin, const u16* __restrict__ a1,
                          const u16* __restrict__ a2, const float* __restrict__ gamma,
                          const float* __restrict__ beta, float* __restrict__ hf,
                          u16* __restrict__ hb) {
  int row = blockIdx.x * 4 + (threadIdx.x >> 6);
  int lane = threadIdx.x & 63;
  size_t base = (size_t)row * 512 + lane * 8;
  float4 h0 = *reinterpret_cast<const float4*>(hin + base);
  float4 h1 = *reinterpret_cast<const float4*>(hin + base + 4);
  s16x8 x1 = *reinterpret_cast<const s16x8*>(a1 + base);
  s16x8 x2 = {};
  if (NADD == 2) x2 = *reinterpret_cast<const s16x8*>(a2 + base);
  float v[8];
  float hv[8] = {h0.x, h0.y, h0.z, h0.w, h1.x, h1.y, h1.z, h1.w};
  float sum = 0.f;
  #pragma unroll
  for (int j = 0; j < 8; j++) {
    float t = hv[j] + bf2f((u16)x1[j]);
    if (NADD == 2) t += bf2f((u16)x2[j]);
    v[j] = t; sum += t;
  }
  #pragma unroll
  for (int o = 32; o >= 1; o >>= 1) sum += __shfl_xor(sum, o, 64);
  float mean = sum * (1.0f / 512.0f);
  float sq = 0.f;
  #pragma unroll
  for (int j = 0; j < 8; j++) { float d = v[j] - mean; sq += d * d; }
  #pragma unroll
  for (int o = 32; o >= 1; o >>= 1) sq += __shfl_xor(sq, o, 64);
  float rstd = rsqrtf(sq * (1.0f / 512.0f) + 1e-5f);
  #pragma unroll
  for (int j = 0; j < 8; j++) {
    int d = lane * 8 + j;
    float o = (v[j] - mean) * rstd * gamma[d] + beta[d];
    hf[base + j] = o;
    hb[base + j] = f2bf(o);
  }
}

// ---------------- final projection (token (s=S-1, b) = b*S + S-1) ----------------
__global__ void out_kernel(const float* __restrict__ hf, const float* __restrict__ Wout,
                           const float* __restrict__ bout, float* __restrict__ out) {
  int b = blockIdx.x; int lane = threadIdx.x;
  size_t base = ((size_t)b * S + S - 1) * 512;
  float s = 0.f;
  #pragma unroll
  for (int j = 0; j < 8; j++) { int d = lane * 8 + j; s += hf[base + d] * Wout[d]; }
  #pragma unroll
  for (int o = 32; o >= 1; o >>= 1) s += __shfl_xor(s, o, 64);
  if (lane == 0) out[b] = s + bout[0];
}

extern "C" void kernel_launch(void* const* d_in, const int* in_sizes, int n_in,
                              void* d_out, int out_size, void* d_ws, size_t ws_size,
                              hipStream_t stream) {
  (void)in_sizes; (void)n_in; (void)out_size; (void)ws_size;
  const float* x      = (const float*)d_in[0];
  const float* W_emb  = (const float*)d_in[1];
  const float* b_emb  = (const float*)d_in[2];
  const float* Wqkv_g = (const float*)d_in[3];
  const float* bqkv_g = (const float*)d_in[4];
  const float* Wo_g   = (const float*)d_in[5];
  const float* bo_g   = (const float*)d_in[6];
  const float* Wqkv_l = (const float*)d_in[7];
  const float* bqkv_l = (const float*)d_in[8];
  const float* Wo_l   = (const float*)d_in[9];
  const float* bo_l   = (const float*)d_in[10];
  const float* W1     = (const float*)d_in[11];
  const float* b1f    = (const float*)d_in[12];
  const float* W2     = (const float*)d_in[13];
  const float* b2f    = (const float*)d_in[14];
  const float* g1     = (const float*)d_in[15];
  const float* be1    = (const float*)d_in[16];
  const float* g2     = (const float*)d_in[17];
  const float* be2    = (const float*)d_in[18];
  const float* W_out  = (const float*)d_in[19];
  const float* b_out  = (const float*)d_in[20];
  float* out = (float*)d_out;

  char* ws = (char*)d_ws;
  u16*   w_bf = (u16*)ws;                       // 32 MiB bf16 weights
  float* h_f  = (float*)(ws + 33554432);        // 32 MiB fp32 master
  u16*   h_b  = (u16*)(ws + 67108864);          // 16 MiB bf16 mirror
  u16*   qkv  = (u16*)(ws + 83886080);          // 64 MiB: [t][2048] = {q_g,k_g,q_l,k_l}
  u16*   ff1  = (u16*)(ws + 83886080);          // aliases qkv (dead by FFN)
  u16*   vpk  = (u16*)(ws + 150994944);         // 32 MiB: v_pk_g | v_pk_l (+8388608 elems)
  u16*   ctx  = (u16*)(ws + 184549376);         // 32 MiB: [t][1024] = ctx_g | ctx_l
  u16*   go   = (u16*)(ws + 218103808);         // 16 MiB bf16 (wo out, also ff2 out) -> 224 MiB

  // fused weight layouts
  u16* wqkvF = w_bf;                 // per layer [3072][512]: rows 0-1535 g, 1536-3071 l
  u16* woF   = w_bf + 6291456;       // per layer [512][1024]: k<512 g, k>=512 l
  u16* w1b   = w_bf + 8388608;
  u16* w2b   = w_bf + 12582912;

  auto cvt = [&](const float* s_, u16* d_, int n) {
    cvt_bf16_kernel<<<(n / 4 + 255) / 256, 256, 0, stream>>>(s_, d_, n / 4);
  };
  for (int i = 0; i < Ln; i++) {
    cvt(Wqkv_g + (size_t)i * 786432, wqkvF + (size_t)i * 1572864, 786432);
    cvt(Wqkv_l + (size_t)i * 786432, wqkvF + (size_t)i * 1572864 + 786432, 786432);
  }
  cvt_wo_kernel<<<2048, 256, 0, stream>>>(Wo_g, Wo_l, woF);
  cvt(W1, w1b, 4194304);
  cvt(W2, w2b, 4194304);

  embed_kernel<<<T, 256, 0, stream>>>(x, W_emb, b_emb, h_f, h_b);

  for (int i = 0; i < Ln; i++) {
    // fused qkv (global+local) with V-transpose epilogue
    gemm_bt_kernel<1, 1, 0><<<dim3(3072 / 128, T / 128), 256, 0, stream>>>(
        h_b, wqkvF + (size_t)i * 1572864, bqkv_g + i * 1536, bqkv_l + i * 1536,
        qkv, vpk, T, 3072, 512);
    // global attention -> ctx[:, 0:512]   (128 q-rows/block: 8h * 16qb * 8b = 1024)
    flash_kernel<<<dim3(1024), 256, 0, stream>>>(qkv, vpk, ctx, 2048, 16, 0, 512, 0);
    // local attention -> ctx[:, 512:1024] (8h * 4qb * 4n * 8b = 1024)
    flash_kernel<<<dim3(1024), 256, 0, stream>>>(qkv, vpk + 8388608, ctx, 512, 4, 1024, 1536, 512);
    // fused output projection: [ctx_g|ctx_l] @ [Wo_g;Wo_l], bias = bo_g + bo_l
    gemm_bt_kernel<1, 0, 1><<<dim3(512 / 128, T / 128), 256, 0, stream>>>(
        ctx, woF + (size_t)i * 524288, bo_g + i * 512, bo_l + i * 512,
        go, nullptr, T, 512, 1024);
    // LN1
    ln_kernel<1><<<T / 4, 256, 0, stream>>>(h_f, go, nullptr, g1 + i * 512, be1 + i * 512, h_f, h_b);
    // FFN
    gemm_bt_kernel<2, 0, 0><<<dim3(FFd / 128, T / 128), 256, 0, stream>>>(
        h_b, w1b + (size_t)i * 1048576, b1f + i * 2048, nullptr, ff1, nullptr, T, 2048, 512);
    gemm_bt_kernel<1, 0, 0><<<dim3(512 / 128, T / 128), 256, 0, stream>>>(
        ff1, w2b + (size_t)i * 1048576, b2f + i * 512, nullptr, go, nullptr, T, 512, 2048);
    ln_kernel<1><<<T / 4, 256, 0, stream>>>(h_f, go, nullptr, g2 + i * 512, be2 + i * 512, h_f, h_b);
  }

  out_kernel<<<Bsz, 64, 0, stream>>>(h_f, W_out, b_out, out);
}

// Round 9
// 1547.891 us; speedup vs baseline: 2.3996x; 1.0717x over previous
//
#include <hip/hip_runtime.h>
#include <hip/hip_bf16.h>

#define DEV __device__ __forceinline__

typedef __attribute__((ext_vector_type(4))) float f32x4;
typedef __attribute__((ext_vector_type(8))) short s16x8;
typedef unsigned short u16;

constexpr int Bsz = 8;      // batch
constexpr int S   = 2048;   // sequence
constexpr int Dm  = 512;    // model dim
constexpr int NHd = 8;      // heads
constexpr int FFd = 2048;
constexpr int Ln  = 4;
constexpr int T   = S * Bsz; // 16384 tokens; token index t = b*S + s (batch-major)

DEV u16 f2bf(float f) {
  union { float f; unsigned u; } v; v.f = f;
  unsigned r = v.u + 0x7fff + ((v.u >> 16) & 1);
  return (u16)(r >> 16);
}
DEV float bf2f(u16 a) { union { unsigned u; float f; } v; v.u = ((unsigned)a) << 16; return v.f; }
DEV float exp2g(float x) { return __builtin_amdgcn_exp2f(x); }   // v_exp_f32 (base-2 native)

typedef __attribute__((address_space(1))) const unsigned int guint;
typedef __attribute__((address_space(3))) unsigned int luint;
DEV void gload16(const void* g, void* l) {
  __builtin_amdgcn_global_load_lds((guint*)g, (luint*)l, 16, 0, 0);
}

// ---------------- weight fp32 -> bf16 ----------------
__global__ void cvt_bf16_kernel(const float* __restrict__ src, u16* __restrict__ dst, int n4) {
  int i = (blockIdx.x * 256 + threadIdx.x);
  if (i >= n4) return;
  float4 v = *reinterpret_cast<const float4*>(src + i * 4);
  ushort4 o; o.x = f2bf(v.x); o.y = f2bf(v.y); o.z = f2bf(v.z); o.w = f2bf(v.w);
  *reinterpret_cast<ushort4*>(dst + i * 4) = o;
}

// ---------------- Wo fuse: dst[l][n][k], k<512 from Wo_g, else Wo_l (K-concat) ----------------
__global__ void cvt_wo_kernel(const float* __restrict__ g, const float* __restrict__ l,
                              u16* __restrict__ dst) {
  int i = blockIdx.x * 256 + threadIdx.x;          // over 4-elem groups, total L*512*1024/4
  int e = i * 4;
  int li = e >> 19;
  int rem = e & 524287;
  int n = rem >> 10, k = rem & 1023;
  const float* src = (k < 512) ? (g + ((size_t)li * 512 + n) * 512 + k)
                               : (l + ((size_t)li * 512 + n) * 512 + (k - 512));
  float4 v = *reinterpret_cast<const float4*>(src);
  ushort4 o; o.x = f2bf(v.x); o.y = f2bf(v.y); o.z = f2bf(v.z); o.w = f2bf(v.w);
  *reinterpret_cast<ushort4*>(dst + e) = o;
}

// ---------------- embed + positional encoding (token t = b*S + s) ----------------
__global__ void embed_kernel(const float* __restrict__ x, const float* __restrict__ Wemb,
                             const float* __restrict__ bemb, float* __restrict__ hf,
                             u16* __restrict__ hb) {
  int t = blockIdx.x;
  int b = t >> 11, s = t & 2047;
  const float* xr = x + ((size_t)b * S + s) * 14;
  float xv[14];
  #pragma unroll
  for (int i = 0; i < 14; i++) xv[i] = xr[i];
  for (int d = threadIdx.x; d < Dm; d += blockDim.x) {
    const float* wr = Wemb + d * 14;
    float acc = bemb[d];
    #pragma unroll
    for (int i = 0; i < 14; i++) acc += xv[i] * wr[i];
    float ang = (float)s * expf((float)((d >> 1) * 2) * (-9.210340371976184f / 512.0f));
    acc += (d & 1) ? cosf(ang) : sinf(ang);
    hf[(size_t)t * Dm + d] = acc;
    hb[(size_t)t * Dm + d] = f2bf(acc);
  }
}

// ---------------- GEMM: C(M,N) = A(M,K) @ Bt(N,K)^T + bias ----------------
// OMODE: 1 = bf16 out, 2 = bf16 out + relu.
// VPACK (fused qkv GEMM, N=3072): 512-col sections {q_g,k_g,v_g,q_l,k_l,v_l};
//   v-sections scatter transposed into vpk[bh][d][s]; q/k write to qkv[t][2048];
//   bias1 = bqkv_g (cols<1536), bias2 = bqkv_l.
// BSUM: bias = bias1[col] + bias2[col] (fused wo GEMM).
template<int OMODE, int VPACK, int BSUM>
__global__ __launch_bounds__(256, 3)
void gemm_bt_kernel(const u16* __restrict__ A, const u16* __restrict__ Bt,
                    const float* __restrict__ bias1, const float* __restrict__ bias2,
                    void* __restrict__ Cout, u16* __restrict__ vpk,
                    int M, int N, int K) {
  __shared__ __align__(16) u16 As[2][128 * 32];
  __shared__ __align__(16) u16 Bs[2][128 * 32];
  const int tid = threadIdx.x;
  const int lane = tid & 63, w = tid >> 6;
  const int wr = w >> 1, wc = w & 1;
  const int lr = lane & 15, lg = lane >> 4;
  const int m0 = blockIdx.y * 128, n0 = blockIdx.x * 128;

  f32x4 acc[4][4] = {};

  const int c1 = tid, c2 = tid + 256;
  const u16* gA1 = A + (size_t)(m0 + (c1 >> 2)) * K + (c1 & 3) * 8;
  const u16* gA2 = A + (size_t)(m0 + (c2 >> 2)) * K + (c2 & 3) * 8;
  const u16* gB1 = Bt + (size_t)(n0 + (c1 >> 2)) * K + (c1 & 3) * 8;
  const u16* gB2 = Bt + (size_t)(n0 + (c2 >> 2)) * K + (c2 & 3) * 8;

  const int nk = K >> 5;
  auto stage = [&](int t, int c) {
    const int kt = t * 32;
    gload16(gA1 + kt, As[c] + c1 * 8); gload16(gA2 + kt, As[c] + c2 * 8);
    gload16(gB1 + kt, Bs[c] + c1 * 8); gload16(gB2 + kt, Bs[c] + c2 * 8);
  };

  stage(0, 0);
  for (int t = 0; t < nk; ++t) {
    const int c = t & 1;
    if (t + 1 < nk) {
      stage(t + 1, c ^ 1);
      asm volatile("s_waitcnt vmcnt(4)" ::: "memory");
    } else {
      asm volatile("s_waitcnt vmcnt(0)" ::: "memory");
    }
    __builtin_amdgcn_s_barrier();

    s16x8 a[4], bb[4];
    #pragma unroll
    for (int i = 0; i < 4; i++) {
      a[i]  = *reinterpret_cast<const s16x8*>(As[c] + ((wr * 64 + i * 16 + lr) * 32 + lg * 8));
      bb[i] = *reinterpret_cast<const s16x8*>(Bs[c] + ((wc * 64 + i * 16 + lr) * 32 + lg * 8));
    }
    #pragma unroll
    for (int mi = 0; mi < 4; mi++)
      #pragma unroll
      for (int ni = 0; ni < 4; ni++)
        acc[mi][ni] = __builtin_amdgcn_mfma_f32_16x16x32_bf16(a[mi], bb[ni], acc[mi][ni], 0, 0, 0);

    __builtin_amdgcn_s_barrier();
  }

  // epilogue
  const int sec = VPACK ? (n0 >> 9) : 0;            // block-uniform (128 | 512)
  const bool isv = VPACK && (sec == 2 || sec == 5);
  const int ldc = VPACK ? 2048 : N;
  const int csub = (VPACK && sec >= 3) ? 512 : 0;
  u16* vdst = nullptr;
  if (isv) vdst = vpk + (sec == 5 ? 8388608 : 0);

  #pragma unroll
  for (int mi = 0; mi < 4; mi++) {
    int row = m0 + wr * 64 + mi * 16 + lg * 4;
    #pragma unroll
    for (int ni = 0; ni < 4; ni++) {
      int col = n0 + wc * 64 + ni * 16 + lr;
      float bv;
      if (VPACK)      bv = (col < 1536) ? bias1[col] : bias2[col - 1536];
      else if (BSUM)  bv = bias1[col] + bias2[col];
      else            bv = bias1[col];
      if (isv) {
        int vcol = col - (sec == 2 ? 1024 : 2560);
        int hh = vcol >> 6, dd = vcol & 63;
        int bb2 = row >> 11, ss = row & 2047;       // rows = 4 consecutive s within one b
        ushort4 o;
        o.x = f2bf(acc[mi][ni][0] + bv);
        o.y = f2bf(acc[mi][ni][1] + bv);
        o.z = f2bf(acc[mi][ni][2] + bv);
        o.w = f2bf(acc[mi][ni][3] + bv);
        *reinterpret_cast<ushort4*>(vdst + ((size_t)(bb2 * NHd + hh) * 64 + dd) * S + ss) = o;
      } else {
        #pragma unroll
        for (int r = 0; r < 4; r++) {
          float v = acc[mi][ni][r] + bv;
          if (OMODE == 2) v = v > 0.f ? v : 0.f;
          ((u16*)Cout)[(size_t)(row + r) * ldc + (col - csub)] = f2bf(v);
        }
      }
    }
  }
}

// ---------------- flash attention v7: merged global+local, single-drain, 2 q-tiles ----------------
// Grid 2048: bid<1024 -> global (S_att=2048), else local (S_att=512). h = bid&7 (XCD pin).
// Per 64-k iter: QK(A,B) -> softmax+exp+cvt(A,B) -> write p_ldsA/p_ldsB -> ONE lgkmcnt(0)
// -> PV(A)+PV(B). WAR vs prev iter's reads is covered by the end-of-iter __syncthreads drain.
__global__ __launch_bounds__(256, 3)
void flash_kernel(const u16* __restrict__ qkv, const u16* __restrict__ vpk_all,
                  u16* __restrict__ ctx) {
  const int tid = threadIdx.x;
  const int lane = tid & 63, w = tid >> 6;
  const int lr = lane & 15, lg = lane >> 4;
  const int bid = blockIdx.x;
  const int half = bid >> 10;                 // 0 = global, 1 = local
  const int bid10 = bid & 1023;
  const int h = bid10 & 7;
  const int r_ = bid10 >> 3;
  const int S_att = half ? 512 : 2048;
  const int lognqb = half ? 2 : 4;
  const int qb = r_ & ((1 << lognqb) - 1);
  const int cw = r_ >> lognqb;
  const int b = cw & 7, n = cw >> 3;
  const int qoff = half ? 1024 : 0;
  const int koff = half ? 1536 : 512;
  const int coff = half ? 512 : 0;
  const u16* v_pk = vpk_all + (half ? 8388608 : 0);
  const int s_base = n * S_att;
  const int q0A = qb * 128 + w * 16;          // tile A rows
  const int q0B = q0A + 64;                   // tile B rows

  __shared__ __align__(16) u16 KT[2][4096];   // [key 0..63][dk 0..63], seg-swizzled
  __shared__ __align__(16) u16 VT[2][4096];   // [d 0..63][k 0..63],    seg-swizzled
  __shared__ __align__(16) u16 p_lds_all[4][2][16][72];
  u16 (*p_ldsA)[72] = p_lds_all[w][0];
  u16 (*p_ldsB)[72] = p_lds_all[w][1];

  const u16* vbase = v_pk + (size_t)(b * NHd + h) * 64 * S + s_base;

  // Q direct load + scale (0.125 * log2e) + repack to bf16, both tiles
  s16x8 qfA[2], qfB[2];
  {
    const float qs = 0.18033688011112042f;
    const u16* qpA = qkv + ((size_t)b * S + s_base + q0A + lr) * 2048 + qoff + h * 64 + lg * 8;
    const u16* qpB = qkv + ((size_t)b * S + s_base + q0B + lr) * 2048 + qoff + h * 64 + lg * 8;
    s16x8 a0 = *reinterpret_cast<const s16x8*>(qpA);
    s16x8 a1 = *reinterpret_cast<const s16x8*>(qpA + 32);
    s16x8 b0 = *reinterpret_cast<const s16x8*>(qpB);
    s16x8 b1 = *reinterpret_cast<const s16x8*>(qpB + 32);
    #pragma unroll
    for (int j = 0; j < 8; j++) {
      qfA[0][j] = (short)f2bf(bf2f((u16)a0[j]) * qs);
      qfA[1][j] = (short)f2bf(bf2f((u16)a1[j]) * qs);
      qfB[0][j] = (short)f2bf(bf2f((u16)b0[j]) * qs);
      qfB[1][j] = (short)f2bf(bf2f((u16)b1[j]) * qs);
    }
  }

  s16x8 ones;
  #pragma unroll
  for (int j = 0; j < 8; j++) ones[j] = (short)0x3F80;  // bf16 1.0

  float mA = -1e30f, mB = -1e30f;
  f32x4 laccA = (f32x4){0.f, 0.f, 0.f, 0.f}, laccB = (f32x4){0.f, 0.f, 0.f, 0.f};
  f32x4 oaccA[4], oaccB[4];
  #pragma unroll
  for (int nt = 0; nt < 4; nt++) {
    oaccA[nt] = (f32x4){0.f, 0.f, 0.f, 0.f};
    oaccB[nt] = (f32x4){0.f, 0.f, 0.f, 0.f};
  }

  // staging: thread t covers rows (t>>3) and (t>>3)+32, 16B segment (t&7),
  // global source pre-swizzled seg^=(row&7), LDS dest linear (rule #21).
  const int seg = tid & 7, sr1 = tid >> 3, sr2 = (tid >> 3) + 32;
  const int ssw1 = (seg ^ (sr1 & 7)) * 8, ssw2 = (seg ^ (sr2 & 7)) * 8;

  const u16* kroot = qkv + ((size_t)b * S + s_base) * 2048 + koff + h * 64;

  auto stage = [&](int kb, int c) {
    const u16* kt = kroot + (size_t)kb * 2048;
    gload16(kt + (size_t)sr1 * 2048 + ssw1, &KT[c][tid * 8]);
    gload16(kt + (size_t)sr2 * 2048 + ssw2, &KT[c][2048 + tid * 8]);
    const u16* vt = vbase + kb;
    gload16(vt + (size_t)sr1 * S + ssw1, &VT[c][tid * 8]);
    gload16(vt + (size_t)sr2 * S + ssw2, &VT[c][2048 + tid * 8]);
  };

  stage(0, 0);
  __syncthreads();

  for (int kb = 0; kb < S_att; kb += 64) {
    const int c = (kb >> 6) & 1;
    if (kb + 64 < S_att) stage(kb + 64, c ^ 1);   // prefetch: drains at end-of-iter barrier

    // K^T Q for both tiles (16 MFMA)
    f32x4 sgA[4], sgB[4];
    __builtin_amdgcn_s_setprio(1);
    #pragma unroll
    for (int g = 0; g < 4; g++) {
      const int key = g * 16 + lr, kw = key & 7;
      const u16* kp = &KT[c][key * 64];
      s16x8 k0 = *reinterpret_cast<const s16x8*>(kp + ((lg ^ kw) * 8));
      s16x8 k1 = *reinterpret_cast<const s16x8*>(kp + (((4 + lg) ^ kw) * 8));
      f32x4 sa = (f32x4){0.f, 0.f, 0.f, 0.f};
      sa = __builtin_amdgcn_mfma_f32_16x16x32_bf16(k0, qfA[0], sa, 0, 0, 0);
      sa = __builtin_amdgcn_mfma_f32_16x16x32_bf16(k1, qfA[1], sa, 0, 0, 0);
      sgA[g] = sa;
      f32x4 sb = (f32x4){0.f, 0.f, 0.f, 0.f};
      sb = __builtin_amdgcn_mfma_f32_16x16x32_bf16(k0, qfB[0], sb, 0, 0, 0);
      sb = __builtin_amdgcn_mfma_f32_16x16x32_bf16(k1, qfB[1], sb, 0, 0, 0);
      sgB[g] = sb;
    }
    __builtin_amdgcn_s_setprio(0);

    // softmax maxes for both tiles
    float tmA, tmB;
    {
      float t0 = fmaxf(fmaxf(sgA[0][0], sgA[0][1]), fmaxf(sgA[0][2], sgA[0][3]));
      float t1 = fmaxf(fmaxf(sgA[1][0], sgA[1][1]), fmaxf(sgA[1][2], sgA[1][3]));
      float t2 = fmaxf(fmaxf(sgA[2][0], sgA[2][1]), fmaxf(sgA[2][2], sgA[2][3]));
      float t3 = fmaxf(fmaxf(sgA[3][0], sgA[3][1]), fmaxf(sgA[3][2], sgA[3][3]));
      tmA = fmaxf(fmaxf(t0, t1), fmaxf(t2, t3));
      tmA = fmaxf(tmA, __shfl_xor(tmA, 16, 64));
      tmA = fmaxf(tmA, __shfl_xor(tmA, 32, 64));
      float u0 = fmaxf(fmaxf(sgB[0][0], sgB[0][1]), fmaxf(sgB[0][2], sgB[0][3]));
      float u1 = fmaxf(fmaxf(sgB[1][0], sgB[1][1]), fmaxf(sgB[1][2], sgB[1][3]));
      float u2 = fmaxf(fmaxf(sgB[2][0], sgB[2][1]), fmaxf(sgB[2][2], sgB[2][3]));
      float u3 = fmaxf(fmaxf(sgB[3][0], sgB[3][1]), fmaxf(sgB[3][2], sgB[3][3]));
      tmB = fmaxf(fmaxf(u0, u1), fmaxf(u2, u3));
      tmB = fmaxf(tmB, __shfl_xor(tmB, 16, 64));
      tmB = fmaxf(tmB, __shfl_xor(tmB, 32, 64));
    }
    if (__any((int)(tmA > mA + 8.f))) {          // defer-max tile A
      float mnew = fmaxf(mA, tmA);
      float cf = exp2g(mA - mnew);
      mA = mnew;
      #pragma unroll
      for (int r = 0; r < 4; r++) {
        float co = __shfl(cf, lg * 4 + r, 16);
        laccA[r] *= co;
        #pragma unroll
        for (int nt = 0; nt < 4; nt++) oaccA[nt][r] *= co;
      }
    }
    if (__any((int)(tmB > mB + 8.f))) {          // defer-max tile B
      float mnew = fmaxf(mB, tmB);
      float cf = exp2g(mB - mnew);
      mB = mnew;
      #pragma unroll
      for (int r = 0; r < 4; r++) {
        float co = __shfl(cf, lg * 4 + r, 16);
        laccB[r] *= co;
        #pragma unroll
        for (int nt = 0; nt < 4; nt++) oaccB[nt][r] *= co;
      }
    }

    // exp + pack + write BOTH tiles (separate LDS regions), then one drain
    #pragma unroll
    for (int g = 0; g < 4; g++) {
      float e0 = exp2g(sgA[g][0] - mA);
      float e1 = exp2g(sgA[g][1] - mA);
      float e2 = exp2g(sgA[g][2] - mA);
      float e3 = exp2g(sgA[g][3] - mA);
      unsigned p01, p23;
      asm("v_cvt_pk_bf16_f32 %0, %1, %2" : "=v"(p01) : "v"(e0), "v"(e1));
      asm("v_cvt_pk_bf16_f32 %0, %1, %2" : "=v"(p23) : "v"(e2), "v"(e3));
      uint2 pk; pk.x = p01; pk.y = p23;
      *reinterpret_cast<uint2*>(&p_ldsA[lr][g * 16 + lg * 4]) = pk;
    }
    #pragma unroll
    for (int g = 0; g < 4; g++) {
      float e0 = exp2g(sgB[g][0] - mB);
      float e1 = exp2g(sgB[g][1] - mB);
      float e2 = exp2g(sgB[g][2] - mB);
      float e3 = exp2g(sgB[g][3] - mB);
      unsigned p01, p23;
      asm("v_cvt_pk_bf16_f32 %0, %1, %2" : "=v"(p01) : "v"(e0), "v"(e1));
      asm("v_cvt_pk_bf16_f32 %0, %1, %2" : "=v"(p23) : "v"(e2), "v"(e3));
      uint2 pk; pk.x = p01; pk.y = p23;
      *reinterpret_cast<uint2*>(&p_ldsB[lr][g * 16 + lg * 4]) = pk;
    }
    asm volatile("s_waitcnt lgkmcnt(0)" ::: "memory");  // RAW: all P writes visible

    // PV both tiles
    __builtin_amdgcn_s_setprio(1);
    #pragma unroll
    for (int kc = 0; kc < 2; kc++) {
      s16x8 paA = *reinterpret_cast<const s16x8*>(&p_ldsA[lr][kc * 32 + lg * 8]);
      s16x8 paB = *reinterpret_cast<const s16x8*>(&p_ldsB[lr][kc * 32 + lg * 8]);
      laccA = __builtin_amdgcn_mfma_f32_16x16x32_bf16(paA, ones, laccA, 0, 0, 0);
      laccB = __builtin_amdgcn_mfma_f32_16x16x32_bf16(paB, ones, laccB, 0, 0, 0);
      #pragma unroll
      for (int nt = 0; nt < 4; nt++) {
        const int d = nt * 16 + lr;
        s16x8 vfr = *reinterpret_cast<const s16x8*>(
            &VT[c][d * 64 + (((kc * 4 + lg) ^ (d & 7)) * 8)]);
        oaccA[nt] = __builtin_amdgcn_mfma_f32_16x16x32_bf16(paA, vfr, oaccA[nt], 0, 0, 0);
        oaccB[nt] = __builtin_amdgcn_mfma_f32_16x16x32_bf16(paB, vfr, oaccB[nt], 0, 0, 0);
      }
    }
    __builtin_amdgcn_s_setprio(0);

    __syncthreads();  // drains stage vmcnt + all LDS reads; flips buffers safely
  }

  #pragma unroll
  for (int nt = 0; nt < 4; nt++)
    #pragma unroll
    for (int r = 0; r < 4; r++) {
      float vA = oaccA[nt][r] / laccA[r];
      size_t tqA = (size_t)b * S + s_base + q0A + lg * 4 + r;
      ctx[tqA * 1024 + coff + h * 64 + nt * 16 + lr] = f2bf(vA);
      float vB = oaccB[nt][r] / laccB[r];
      size_t tqB = (size_t)b * S + s_base + q0B + lg * 4 + r;
      ctx[tqB * 1024 + coff + h * 64 + nt * 16 + lr] = f2bf(vB);
    }
}

// ---------------- residual add (bf16 branch) + LayerNorm ----------------
template<int NADD>
__global__ void ln_kernel(const float* __restrict__ hin, const u16* __restrict__ a1,
                          const u16* __restrict__ a2, const float* __restrict__ gamma,
                          const float* __restrict__ beta, float* __restrict__ hf,
                          u16* __restrict__ hb) {
  int row = blockIdx.x * 4 + (threadIdx.x >> 6);
  int lane = threadIdx.x & 63;
  size_t base = (size_t)row * 512 + lane * 8;
  float4 h0 = *reinterpret_cast<const float4*>(hin + base);
  float4 h1 = *reinterpret_cast<const float4*>(hin + base + 4);
  s16x8 x1 = *reinterpret_cast<const s16x8*>(a1 + base);
  s16x8 x2 = {};
  if (NADD == 2) x2 = *reinterpret_cast<const s16x8*>(a2 + base);
  float v[8];
  float hv[8] = {h0.x, h0.y, h0.z, h0.w, h1.x, h1.y, h1.z, h1.w};
  float sum = 0.f;
  #pragma unroll
  for (int j = 0; j < 8; j++) {
    float t = hv[j] + bf2f((u16)x1[j]);
    if (NADD == 2) t += bf2f((u16)x2[j]);
    v[j] = t; sum += t;
  }
  #pragma unroll
  for (int o = 32; o >= 1; o >>= 1) sum += __shfl_xor(sum, o, 64);
  float mean = sum * (1.0f / 512.0f);
  float sq = 0.f;
  #pragma unroll
  for (int j = 0; j < 8; j++) { float d = v[j] - mean; sq += d * d; }
  #pragma unroll
  for (int o = 32; o >= 1; o >>= 1) sq += __shfl_xor(sq, o, 64);
  float rstd = rsqrtf(sq * (1.0f / 512.0f) + 1e-5f);
  #pragma unroll
  for (int j = 0; j < 8; j++) {
    int d = lane * 8 + j;
    float o = (v[j] - mean) * rstd * gamma[d] + beta[d];
    hf[base + j] = o;
    hb[base + j] = f2bf(o);
  }
}

// ---------------- final projection (token (s=S-1, b) = b*S + S-1) ----------------
__global__ void out_kernel(const float* __restrict__ hf, const float* __restrict__ Wout,
                           const float* __restrict__ bout, float* __restrict__ out) {
  int b = blockIdx.x; int lane = threadIdx.x;
  size_t base = ((size_t)b * S + S - 1) * 512;
  float s = 0.f;
  #pragma unroll
  for (int j = 0; j < 8; j++) { int d = lane * 8 + j; s += hf[base + d] * Wout[d]; }
  #pragma unroll
  for (int o = 32; o >= 1; o >>= 1) s += __shfl_xor(s, o, 64);
  if (lane == 0) out[b] = s + bout[0];
}

extern "C" void kernel_launch(void* const* d_in, const int* in_sizes, int n_in,
                              void* d_out, int out_size, void* d_ws, size_t ws_size,
                              hipStream_t stream) {
  (void)in_sizes; (void)n_in; (void)out_size; (void)ws_size;
  const float* x      = (const float*)d_in[0];
  const float* W_emb  = (const float*)d_in[1];
  const float* b_emb  = (const float*)d_in[2];
  const float* Wqkv_g = (const float*)d_in[3];
  const float* bqkv_g = (const float*)d_in[4];
  const float* Wo_g   = (const float*)d_in[5];
  const float* bo_g   = (const float*)d_in[6];
  const float* Wqkv_l = (const float*)d_in[7];
  const float* bqkv_l = (const float*)d_in[8];
  const float* Wo_l   = (const float*)d_in[9];
  const float* bo_l   = (const float*)d_in[10];
  const float* W1     = (const float*)d_in[11];
  const float* b1f    = (const float*)d_in[12];
  const float* W2     = (const float*)d_in[13];
  const float* b2f    = (const float*)d_in[14];
  const float* g1     = (const float*)d_in[15];
  const float* be1    = (const float*)d_in[16];
  const float* g2     = (const float*)d_in[17];
  const float* be2    = (const float*)d_in[18];
  const float* W_out  = (const float*)d_in[19];
  const float* b_out  = (const float*)d_in[20];
  float* out = (float*)d_out;

  char* ws = (char*)d_ws;
  u16*   w_bf = (u16*)ws;                       // 32 MiB bf16 weights
  float* h_f  = (float*)(ws + 33554432);        // 32 MiB fp32 master
  u16*   h_b  = (u16*)(ws + 67108864);          // 16 MiB bf16 mirror
  u16*   qkv  = (u16*)(ws + 83886080);          // 64 MiB: [t][2048] = {q_g,k_g,q_l,k_l}
  u16*   ff1  = (u16*)(ws + 83886080);          // aliases qkv (dead by FFN)
  u16*   vpk  = (u16*)(ws + 150994944);         // 32 MiB: v_pk_g | v_pk_l (+8388608 elems)
  u16*   ctx  = (u16*)(ws + 184549376);         // 32 MiB: [t][1024] = ctx_g | ctx_l
  u16*   go   = (u16*)(ws + 218103808);         // 16 MiB bf16 (wo out, also ff2 out) -> 224 MiB

  // fused weight layouts
  u16* wqkvF = w_bf;                 // per layer [3072][512]: rows 0-1535 g, 1536-3071 l
  u16* woF   = w_bf + 6291456;       // per layer [512][1024]: k<512 g, k>=512 l
  u16* w1b   = w_bf + 8388608;
  u16* w2b   = w_bf + 12582912;

  auto cvt = [&](const float* s_, u16* d_, int n) {
    cvt_bf16_kernel<<<(n / 4 + 255) / 256, 256, 0, stream>>>(s_, d_, n / 4);
  };
  for (int i = 0; i < Ln; i++) {
    cvt(Wqkv_g + (size_t)i * 786432, wqkvF + (size_t)i * 1572864, 786432);
    cvt(Wqkv_l + (size_t)i * 786432, wqkvF + (size_t)i * 1572864 + 786432, 786432);
  }
  cvt_wo_kernel<<<2048, 256, 0, stream>>>(Wo_g, Wo_l, woF);
  cvt(W1, w1b, 4194304);
  cvt(W2, w2b, 4194304);

  embed_kernel<<<T, 256, 0, stream>>>(x, W_emb, b_emb, h_f, h_b);

  for (int i = 0; i < Ln; i++) {
    // fused qkv (global+local) with V-transpose epilogue
    gemm_bt_kernel<1, 1, 0><<<dim3(3072 / 128, T / 128), 256, 0, stream>>>(
        h_b, wqkvF + (size_t)i * 1572864, bqkv_g + i * 1536, bqkv_l + i * 1536,
        qkv, vpk, T, 3072, 512);
    // merged global+local attention (one launch, 2048 blocks)
    flash_kernel<<<dim3(2048), 256, 0, stream>>>(qkv, vpk, ctx);
    // fused output projection: [ctx_g|ctx_l] @ [Wo_g;Wo_l], bias = bo_g + bo_l
    gemm_bt_kernel<1, 0, 1><<<dim3(512 / 128, T / 128), 256, 0, stream>>>(
        ctx, woF + (size_t)i * 524288, bo_g + i * 512, bo_l + i * 512,
        go, nullptr, T, 512, 1024);
    // LN1
    ln_kernel<1><<<T / 4, 256, 0, stream>>>(h_f, go, nullptr, g1 + i * 512, be1 + i * 512, h_f, h_b);
    // FFN
    gemm_bt_kernel<2, 0, 0><<<dim3(FFd / 128, T / 128), 256, 0, stream>>>(
        h_b, w1b + (size_t)i * 1048576, b1f + i * 2048, nullptr, ff1, nullptr, T, 2048, 512);
    gemm_bt_kernel<1, 0, 0><<<dim3(512 / 128, T / 128), 256, 0, stream>>>(
        ff1, w2b + (size_t)i * 1048576, b2f + i * 512, nullptr, go, nullptr, T, 512, 2048);
    ln_kernel<1><<<T / 4, 256, 0, stream>>>(h_f, go, nullptr, g2 + i * 512, be2 + i * 512, h_f, h_b);
  }

  out_kernel<<<Bsz, 64, 0, stream>>>(h_f, W_out, b_out, out);
}